// Round 1
// baseline (504.055 us; speedup 1.0000x reference)
//
#include <hip/hip_runtime.h>

#define F0 512
#define F1 128
#define F2 40

// ---------------- utility ----------------
__global__ void zero_i32(int* a, int n) {
    int i = blockIdx.x * blockDim.x + threadIdx.x;
    int stride = gridDim.x * blockDim.x;
    for (; i < n; i += stride) a[i] = 0;
}

__global__ void degree_kernel(const int* __restrict__ src, const int* __restrict__ dst,
                              int* __restrict__ deg_src, int* __restrict__ deg_dst, int E) {
    int i = blockIdx.x * blockDim.x + threadIdx.x;
    int stride = gridDim.x * blockDim.x;
    for (; i < E; i += stride) {
        atomicAdd(&deg_src[src[i]], 1);
        atomicAdd(&deg_dst[dst[i]], 1);
    }
}

__global__ void norm_kernel(const int* __restrict__ deg_src, const int* __restrict__ deg_dst,
                            float* __restrict__ norm_src, float* __restrict__ norm_dst, int n) {
    int i = blockIdx.x * blockDim.x + threadIdx.x;
    int stride = gridDim.x * blockDim.x;
    for (; i < n; i += stride) {
        int ds = deg_src[i];
        int dd = deg_dst[i];
        norm_src[i] = ds > 0 ? rsqrtf((float)ds) : 0.f;
        norm_dst[i] = dd > 0 ? rsqrtf((float)dd) : 0.f;
    }
}

// single-block exclusive scan (n ~ 50000, runs in a few us)
__global__ __launch_bounds__(1024) void scan_kernel(const int* __restrict__ deg,
                                                    int* __restrict__ row_off, int n) {
    __shared__ int sm[1024];
    __shared__ int carry_s;
    if (threadIdx.x == 0) { carry_s = 0; row_off[0] = 0; }
    __syncthreads();
    for (int base = 0; base < n; base += 1024) {
        int i = base + (int)threadIdx.x;
        int v = (i < n) ? deg[i] : 0;
        sm[threadIdx.x] = v;
        __syncthreads();
        for (int off = 1; off < 1024; off <<= 1) {
            int t = (threadIdx.x >= (unsigned)off) ? sm[threadIdx.x - off] : 0;
            __syncthreads();
            sm[threadIdx.x] += t;
            __syncthreads();
        }
        if (i < n) row_off[i + 1] = carry_s + sm[threadIdx.x];
        __syncthreads();
        if (threadIdx.x == 0) carry_s += sm[1023];
        __syncthreads();
    }
}

__global__ void binning_kernel(const int* __restrict__ src, const int* __restrict__ dst,
                               const int* __restrict__ row_off, int* __restrict__ cursor,
                               int* __restrict__ edge_src, int E) {
    int i = blockIdx.x * blockDim.x + threadIdx.x;
    int stride = gridDim.x * blockDim.x;
    for (; i < E; i += stride) {
        int d = dst[i];
        int pos = row_off[d] + atomicAdd(&cursor[d], 1);
        edge_src[pos] = src[i];
    }
}

// ---------------- GEMM1: h1g = (x * norm_src) @ W1  [n x 512] @ [512 x 128] ----------------
// 32 (M) x 128 (N) tile per block, 256 threads, each thread 4x4 micro-tile.
__global__ __launch_bounds__(256)
void gemm1_kernel(const float* __restrict__ x, const float* __restrict__ W1,
                  const float* __restrict__ norm_src, float* __restrict__ h1g, int n) {
    __shared__ __align__(16) float As[32][36];   // [k][m], padded
    __shared__ __align__(16) float Bs[32][128];  // [k][c]
    const int tid = threadIdx.x;
    const int tx = tid & 31;   // col group: cols tx*4 .. tx*4+3
    const int ty = tid >> 5;   // row group: rows ty*4 .. ty*4+3
    const int block_m = blockIdx.x * 32;

    float acc[4][4] = {};

    const int lm = tid >> 3;         // 0..31 : node row within tile (A load)
    const int lk = (tid & 7) * 4;    // 0..28 : k offset within tile (A load)

    for (int k0 = 0; k0 < F0; k0 += 32) {
        // stage A (transposed) — one float4 per thread
        float4 va = make_float4(0.f, 0.f, 0.f, 0.f);
        int arow = block_m + lm;
        if (arow < n)
            va = *reinterpret_cast<const float4*>(&x[(size_t)arow * F0 + k0 + lk]);
        As[lk + 0][lm] = va.x;
        As[lk + 1][lm] = va.y;
        As[lk + 2][lm] = va.z;
        As[lk + 3][lm] = va.w;
        // stage B — four float4 per thread
#pragma unroll
        for (int i = 0; i < 4; i++) {
            int s = tid + i * 256;
            int kk = s >> 5;
            int cc = (s & 31) << 2;
            *reinterpret_cast<float4*>(&Bs[kk][cc]) =
                *reinterpret_cast<const float4*>(&W1[(size_t)(k0 + kk) * F1 + cc]);
        }
        __syncthreads();
#pragma unroll
        for (int kk = 0; kk < 32; ++kk) {
            float4 a = *reinterpret_cast<const float4*>(&As[kk][ty << 2]);
            float4 b = *reinterpret_cast<const float4*>(&Bs[kk][tx << 2]);
            acc[0][0] += a.x * b.x; acc[0][1] += a.x * b.y; acc[0][2] += a.x * b.z; acc[0][3] += a.x * b.w;
            acc[1][0] += a.y * b.x; acc[1][1] += a.y * b.y; acc[1][2] += a.y * b.z; acc[1][3] += a.y * b.w;
            acc[2][0] += a.z * b.x; acc[2][1] += a.z * b.y; acc[2][2] += a.z * b.z; acc[2][3] += a.z * b.w;
            acc[3][0] += a.w * b.x; acc[3][1] += a.w * b.y; acc[3][2] += a.w * b.z; acc[3][3] += a.w * b.w;
        }
        __syncthreads();
    }
#pragma unroll
    for (int i = 0; i < 4; i++) {
        int row = block_m + (ty << 2) + i;
        if (row < n) {
            float nrm = norm_src[row];
            float4 o = make_float4(acc[i][0] * nrm, acc[i][1] * nrm,
                                   acc[i][2] * nrm, acc[i][3] * nrm);
            *reinterpret_cast<float4*>(&h1g[(size_t)row * F1 + (tx << 2)]) = o;
        }
    }
}

// ---------------- Agg1: h1 = relu(segsum(h1g[src]) * norm_dst + b1), one wave per node ----------------
__global__ __launch_bounds__(256)
void agg1_kernel(const float* __restrict__ h1g, const int* __restrict__ row_off,
                 const int* __restrict__ edge_src, const float* __restrict__ norm_dst,
                 const float* __restrict__ b1, float* __restrict__ h1, int n) {
    int wid = (blockIdx.x * blockDim.x + threadIdx.x) >> 6;
    int lane = threadIdx.x & 63;
    if (wid >= n) return;
    int beg = row_off[wid], end = row_off[wid + 1];
    float a0 = 0.f, a1 = 0.f;
    for (int e = beg; e < end; ++e) {
        int s = edge_src[e];
        float2 v = *reinterpret_cast<const float2*>(&h1g[(size_t)s * F1 + lane * 2]);
        a0 += v.x;
        a1 += v.y;
    }
    float nd = norm_dst[wid];
    float o0 = fmaxf(a0 * nd + b1[lane * 2 + 0], 0.f);
    float o1 = fmaxf(a1 * nd + b1[lane * 2 + 1], 0.f);
    *reinterpret_cast<float2*>(&h1[(size_t)wid * F1 + lane * 2]) = make_float2(o0, o1);
}

// ---------------- GEMM2: h2g = (h1 * norm_src) @ W2  [n x 128] @ [128 x 40] ----------------
__global__ __launch_bounds__(256)
void gemm2_kernel(const float* __restrict__ h1, const float* __restrict__ W2,
                  const float* __restrict__ norm_src, float* __restrict__ h2g, int n) {
    __shared__ float W2s[F1][F2];  // 20.5 KB
    for (int i = threadIdx.x; i < F1 * F2; i += 256)
        W2s[i / F2][i % F2] = W2[i];
    __syncthreads();
    int node = blockIdx.x * 256 + threadIdx.x;
    if (node >= n) return;
    float nrm = norm_src[node];
    float acc[F2];
#pragma unroll
    for (int c = 0; c < F2; c++) acc[c] = 0.f;
    const float* row = &h1[(size_t)node * F1];
    for (int k = 0; k < F1; k += 4) {
        float4 a = *reinterpret_cast<const float4*>(&row[k]);
#pragma unroll
        for (int c = 0; c < F2; c++) {
            acc[c] += a.x * W2s[k + 0][c] + a.y * W2s[k + 1][c] +
                      a.z * W2s[k + 2][c] + a.w * W2s[k + 3][c];
        }
    }
    float* orow = &h2g[(size_t)node * F2];
#pragma unroll
    for (int c = 0; c < F2; c++) orow[c] = acc[c] * nrm;
}

// ---------------- Agg2: out = segsum(h2g[src]) * norm_dst + b2, one wave per node ----------------
__global__ __launch_bounds__(256)
void agg2_kernel(const float* __restrict__ h2g, const int* __restrict__ row_off,
                 const int* __restrict__ edge_src, const float* __restrict__ norm_dst,
                 const float* __restrict__ b2, float* __restrict__ out, int n) {
    int wid = (blockIdx.x * blockDim.x + threadIdx.x) >> 6;
    int lane = threadIdx.x & 63;
    if (wid >= n) return;
    int beg = row_off[wid], end = row_off[wid + 1];
    float a = 0.f;
    for (int e = beg; e < end; ++e) {
        int s = edge_src[e];
        if (lane < F2) a += h2g[(size_t)s * F2 + lane];
    }
    if (lane < F2) {
        float nd = norm_dst[wid];
        out[(size_t)wid * F2 + lane] = a * nd + b2[lane];
    }
}

extern "C" void kernel_launch(void* const* d_in, const int* in_sizes, int n_in,
                              void* d_out, int out_size, void* d_ws, size_t ws_size,
                              hipStream_t stream) {
    const float* x  = (const float*)d_in[0];
    const float* W1 = (const float*)d_in[1];
    const float* b1 = (const float*)d_in[2];
    const float* W2 = (const float*)d_in[3];
    const float* b2 = (const float*)d_in[4];
    const int* src  = (const int*)d_in[5];
    const int* dst  = (const int*)d_in[6];
    float* out = (float*)d_out;

    const int n = in_sizes[0] / F0;
    const int E = in_sizes[5];

    // workspace carve-up
    char* ws = (char*)d_ws;
    auto alloc = [&](size_t bytes) -> char* {
        char* p = ws;
        ws += (bytes + 255) & ~(size_t)255;
        return p;
    };
    int* deg_src   = (int*)alloc((size_t)n * 4);
    int* deg_dst   = (int*)alloc((size_t)n * 4);
    int* cursor    = (int*)alloc((size_t)n * 4);
    int* row_off   = (int*)alloc((size_t)(n + 1) * 4);
    int* edge_srcs = (int*)alloc((size_t)E * 4);
    float* norm_src_d = (float*)alloc((size_t)n * 4);
    float* norm_dst_d = (float*)alloc((size_t)n * 4);
    float* h1g = (float*)alloc((size_t)n * F1 * 4);
    float* h1  = (float*)alloc((size_t)n * F1 * 4);
    float* h2g = h1g;  // reuse: h1g dead after agg1 (h2g needs n*F2*4 <= n*F1*4)

    // 1. zero counters
    zero_i32<<<256, 256, 0, stream>>>(deg_src, n);
    zero_i32<<<256, 256, 0, stream>>>(deg_dst, n);
    zero_i32<<<256, 256, 0, stream>>>(cursor, n);
    // 2. degrees
    degree_kernel<<<2048, 256, 0, stream>>>(src, dst, deg_src, deg_dst, E);
    // 3. norms
    norm_kernel<<<(n + 255) / 256, 256, 0, stream>>>(deg_src, deg_dst, norm_src_d, norm_dst_d, n);
    // 4. CSR row offsets (by dst)
    scan_kernel<<<1, 1024, 0, stream>>>(deg_dst, row_off, n);
    // 5. bin edges by dst
    binning_kernel<<<2048, 256, 0, stream>>>(src, dst, row_off, cursor, edge_srcs, E);
    // 6. layer-1 GEMM
    gemm1_kernel<<<(n + 31) / 32, 256, 0, stream>>>(x, W1, norm_src_d, h1g, n);
    // 7. layer-1 aggregate + bias + relu
    agg1_kernel<<<(n + 3) / 4, 256, 0, stream>>>(h1g, row_off, edge_srcs, norm_dst_d, b1, h1, n);
    // 8. layer-2 GEMM
    gemm2_kernel<<<(n + 255) / 256, 256, 0, stream>>>(h1, W2, norm_src_d, h2g, n);
    // 9. layer-2 aggregate + bias
    agg2_kernel<<<(n + 3) / 4, 256, 0, stream>>>(h2g, row_off, edge_srcs, norm_dst_d, b2, out, n);
}

// Round 2
// 280.416 us; speedup vs baseline: 1.7975x; 1.7975x over previous
//
#include <hip/hip_runtime.h>

#define F0 512
#define F1 128
#define F2 40

typedef __attribute__((ext_vector_type(8))) short bf16x8;
typedef __attribute__((ext_vector_type(4))) float f32x4;

__device__ inline ushort f2bf(float f) {
    union { float f; uint u; } v; v.f = f;
    uint u = v.u;
    uint r = u + 0x7fffu + ((u >> 16) & 1u);   // RNE
    return (ushort)(r >> 16);
}
__device__ inline float bf2f(ushort h) {
    union { uint u; float f; } v; v.u = ((uint)h) << 16;
    return v.f;
}

// ---------------- utility ----------------
__global__ void zero_i32(int* a, int n) {
    int i = blockIdx.x * blockDim.x + threadIdx.x;
    int stride = gridDim.x * blockDim.x;
    for (; i < n; i += stride) a[i] = 0;
}

__global__ void degree_kernel(const int* __restrict__ src, const int* __restrict__ dst,
                              int* __restrict__ deg_src, int* __restrict__ deg_dst, int E) {
    int i = blockIdx.x * blockDim.x + threadIdx.x;
    int stride = gridDim.x * blockDim.x;
    for (; i < E; i += stride) {
        atomicAdd(&deg_src[src[i]], 1);
        atomicAdd(&deg_dst[dst[i]], 1);
    }
}

__global__ void norm_kernel(const int* __restrict__ deg_src, const int* __restrict__ deg_dst,
                            float* __restrict__ norm_src, float* __restrict__ norm_dst, int n) {
    int i = blockIdx.x * blockDim.x + threadIdx.x;
    int stride = gridDim.x * blockDim.x;
    for (; i < n; i += stride) {
        int ds = deg_src[i];
        int dd = deg_dst[i];
        norm_src[i] = ds > 0 ? rsqrtf((float)ds) : 0.f;
        norm_dst[i] = dd > 0 ? rsqrtf((float)dd) : 0.f;
    }
}

// ---------------- hierarchical scan (3 kernels) ----------------
__global__ __launch_bounds__(256)
void scan_block_kernel(const int* __restrict__ deg, int* __restrict__ row_off,
                       int* __restrict__ bsum, int n) {
    __shared__ int sm[256];
    int i = blockIdx.x * 256 + threadIdx.x;
    int v = (i < n) ? deg[i] : 0;
    sm[threadIdx.x] = v;
    __syncthreads();
    for (int off = 1; off < 256; off <<= 1) {
        int t = (threadIdx.x >= (unsigned)off) ? sm[threadIdx.x - off] : 0;
        __syncthreads();
        sm[threadIdx.x] += t;
        __syncthreads();
    }
    if (i < n) row_off[i + 1] = sm[threadIdx.x];
    if (threadIdx.x == 255) bsum[blockIdx.x] = sm[255];
}

__global__ __launch_bounds__(256)
void scan_sums_kernel(int* __restrict__ bsum, int nb) {
    __shared__ int sm[256];
    int v = ((int)threadIdx.x < nb) ? bsum[threadIdx.x] : 0;
    sm[threadIdx.x] = v;
    __syncthreads();
    for (int off = 1; off < 256; off <<= 1) {
        int t = (threadIdx.x >= (unsigned)off) ? sm[threadIdx.x - off] : 0;
        __syncthreads();
        sm[threadIdx.x] += t;
        __syncthreads();
    }
    if ((int)threadIdx.x < nb) bsum[threadIdx.x] = sm[threadIdx.x];  // inclusive
}

__global__ void scan_add_kernel(int* __restrict__ row_off, const int* __restrict__ bsum, int n) {
    int i = blockIdx.x * blockDim.x + threadIdx.x;
    int stride = gridDim.x * blockDim.x;
    for (int j = i; j < n; j += stride) {
        int b = j >> 8;
        int add = (b > 0) ? bsum[b - 1] : 0;
        row_off[j + 1] += add;
    }
    if (i == 0) row_off[0] = 0;
}

__global__ void binning_kernel(const int* __restrict__ src, const int* __restrict__ dst,
                               const int* __restrict__ row_off, int* __restrict__ cursor,
                               int* __restrict__ edge_src, int E) {
    int i = blockIdx.x * blockDim.x + threadIdx.x;
    int stride = gridDim.x * blockDim.x;
    for (; i < E; i += stride) {
        int d = dst[i];
        int pos = row_off[d] + atomicAdd(&cursor[d], 1);
        edge_src[pos] = src[i];
    }
}

// ---------------- W1 preconvert: [512][128] f32 -> hi/lo bf16 transposed [128][512] ----------------
__global__ __launch_bounds__(256)
void wconv1_kernel(const float* __restrict__ W1, ushort* __restrict__ Wt_hi,
                   ushort* __restrict__ Wt_lo) {
    int idx = blockIdx.x * 256 + threadIdx.x;  // 0..65535
    int k = idx >> 7, nn = idx & 127;
    float f = W1[idx];
    ushort h = f2bf(f);
    ushort l = f2bf(f - bf2f(h));
    Wt_hi[nn * F0 + k] = h;
    Wt_lo[nn * F0 + k] = l;
}

// ---------------- GEMM1 (MFMA, split bf16): h1g = (x @ W1) * norm_src ----------------
// BM=64 rows, BN=128 (full), BK=32. 4 waves as 2x2 grid of 32x64 wave tiles.
#define BM 64
#define BK 32
#define LDA 40  // padded LDS row pitch (bf16 elems): 80B, 16B-aligned, conflict-free-ish
__global__ __launch_bounds__(256)
void gemm1_mfma(const float* __restrict__ x, const ushort* __restrict__ Wt_hi,
                const ushort* __restrict__ Wt_lo, const float* __restrict__ norm_src,
                float* __restrict__ h1g, int n) {
    __shared__ __align__(16) ushort Ahi[BM][LDA];
    __shared__ __align__(16) ushort Alo[BM][LDA];
    __shared__ __align__(16) ushort Bhi[F1][LDA];
    __shared__ __align__(16) ushort Blo[F1][LDA];

    const int tid = threadIdx.x;
    const int lane = tid & 63;
    const int w = tid >> 6;           // 0..3
    const int wm = (w >> 1) * 32;     // wave row base: 0 / 32
    const int wn = (w & 1) * 64;      // wave col base: 0 / 64
    const int bm = blockIdx.x * BM;
    const int l15 = lane & 15;
    const int lq = lane >> 4;         // 0..3

    const int ar = tid >> 2;          // A stage: row 0..63
    const int ak = (tid & 3) * 8;     // A stage: k offset 0/8/16/24
    const int br = tid >> 1;          // B stage: n-row 0..127
    const int bk = (tid & 1) * 16;    // B stage: k offset 0/16

    f32x4 acc[2][4] = {};

    for (int k0 = 0; k0 < F0; k0 += BK) {
        // ---- stage A: load f32, split to hi/lo bf16 ----
        {
            float vv[8];
            int row = bm + ar;
            if (row < n) {
                float4 p0 = *reinterpret_cast<const float4*>(&x[(size_t)row * F0 + k0 + ak]);
                float4 p1 = *reinterpret_cast<const float4*>(&x[(size_t)row * F0 + k0 + ak + 4]);
                vv[0] = p0.x; vv[1] = p0.y; vv[2] = p0.z; vv[3] = p0.w;
                vv[4] = p1.x; vv[5] = p1.y; vv[6] = p1.z; vv[7] = p1.w;
            } else {
#pragma unroll
                for (int j = 0; j < 8; j++) vv[j] = 0.f;
            }
            ushort hi[8], lo[8];
#pragma unroll
            for (int j = 0; j < 8; j++) {
                hi[j] = f2bf(vv[j]);
                lo[j] = f2bf(vv[j] - bf2f(hi[j]));
            }
            uint4 ph, pl;
            ph.x = (uint)hi[0] | ((uint)hi[1] << 16);
            ph.y = (uint)hi[2] | ((uint)hi[3] << 16);
            ph.z = (uint)hi[4] | ((uint)hi[5] << 16);
            ph.w = (uint)hi[6] | ((uint)hi[7] << 16);
            pl.x = (uint)lo[0] | ((uint)lo[1] << 16);
            pl.y = (uint)lo[2] | ((uint)lo[3] << 16);
            pl.z = (uint)lo[4] | ((uint)lo[5] << 16);
            pl.w = (uint)lo[6] | ((uint)lo[7] << 16);
            *reinterpret_cast<uint4*>(&Ahi[ar][ak]) = ph;
            *reinterpret_cast<uint4*>(&Alo[ar][ak]) = pl;
        }
        // ---- stage B: copy preconverted bf16 (transposed [n][k]) ----
        {
            const uint4* ph = reinterpret_cast<const uint4*>(&Wt_hi[(size_t)br * F0 + k0 + bk]);
            const uint4* pl = reinterpret_cast<const uint4*>(&Wt_lo[(size_t)br * F0 + k0 + bk]);
            uint4 h0 = ph[0], h1v = ph[1];
            uint4 l0 = pl[0], l1 = pl[1];
            *reinterpret_cast<uint4*>(&Bhi[br][bk + 0]) = h0;
            *reinterpret_cast<uint4*>(&Bhi[br][bk + 8]) = h1v;
            *reinterpret_cast<uint4*>(&Blo[br][bk + 0]) = l0;
            *reinterpret_cast<uint4*>(&Blo[br][bk + 8]) = l1;
        }
        __syncthreads();
        // ---- fragments + MFMA ----
        bf16x8 a_hi[2], a_lo[2], b_hi[4], b_lo[4];
#pragma unroll
        for (int mi = 0; mi < 2; mi++) {
            a_hi[mi] = *reinterpret_cast<const bf16x8*>(&Ahi[wm + mi * 16 + l15][lq * 8]);
            a_lo[mi] = *reinterpret_cast<const bf16x8*>(&Alo[wm + mi * 16 + l15][lq * 8]);
        }
#pragma unroll
        for (int ni = 0; ni < 4; ni++) {
            b_hi[ni] = *reinterpret_cast<const bf16x8*>(&Bhi[wn + ni * 16 + l15][lq * 8]);
            b_lo[ni] = *reinterpret_cast<const bf16x8*>(&Blo[wn + ni * 16 + l15][lq * 8]);
        }
#pragma unroll
        for (int mi = 0; mi < 2; mi++) {
#pragma unroll
            for (int ni = 0; ni < 4; ni++) {
                acc[mi][ni] = __builtin_amdgcn_mfma_f32_16x16x32_bf16(a_hi[mi], b_hi[ni], acc[mi][ni], 0, 0, 0);
                acc[mi][ni] = __builtin_amdgcn_mfma_f32_16x16x32_bf16(a_hi[mi], b_lo[ni], acc[mi][ni], 0, 0, 0);
                acc[mi][ni] = __builtin_amdgcn_mfma_f32_16x16x32_bf16(a_lo[mi], b_hi[ni], acc[mi][ni], 0, 0, 0);
            }
        }
        __syncthreads();
    }
    // ---- epilogue: C layout col=lane&15, row=4*(lane>>4)+reg ----
#pragma unroll
    for (int mi = 0; mi < 2; mi++) {
        int rbase = bm + wm + mi * 16 + lq * 4;
#pragma unroll
        for (int r = 0; r < 4; r++) {
            int row = rbase + r;
            if (row < n) {
                float ns = norm_src[row];
#pragma unroll
                for (int ni = 0; ni < 4; ni++) {
                    h1g[(size_t)row * F1 + wn + ni * 16 + l15] = acc[mi][ni][r] * ns;
                }
            }
        }
    }
}

// ---------------- Agg1: h1 = relu(segsum(h1g[src]) * norm_dst + b1), one wave per node ----------------
__global__ __launch_bounds__(256)
void agg1_kernel(const float* __restrict__ h1g, const int* __restrict__ row_off,
                 const int* __restrict__ edge_src, const float* __restrict__ norm_dst,
                 const float* __restrict__ b1, float* __restrict__ h1, int n) {
    int wid = (blockIdx.x * blockDim.x + threadIdx.x) >> 6;
    int lane = threadIdx.x & 63;
    if (wid >= n) return;
    int beg = row_off[wid], end = row_off[wid + 1];
    float a0 = 0.f, a1 = 0.f;
    int e = beg;
    for (; e + 3 < end; e += 4) {
        int s0 = edge_src[e + 0];
        int s1 = edge_src[e + 1];
        int s2 = edge_src[e + 2];
        int s3 = edge_src[e + 3];
        float2 v0 = *reinterpret_cast<const float2*>(&h1g[(size_t)s0 * F1 + lane * 2]);
        float2 v1 = *reinterpret_cast<const float2*>(&h1g[(size_t)s1 * F1 + lane * 2]);
        float2 v2 = *reinterpret_cast<const float2*>(&h1g[(size_t)s2 * F1 + lane * 2]);
        float2 v3 = *reinterpret_cast<const float2*>(&h1g[(size_t)s3 * F1 + lane * 2]);
        a0 += (v0.x + v1.x) + (v2.x + v3.x);
        a1 += (v0.y + v1.y) + (v2.y + v3.y);
    }
    for (; e < end; ++e) {
        int s = edge_src[e];
        float2 v = *reinterpret_cast<const float2*>(&h1g[(size_t)s * F1 + lane * 2]);
        a0 += v.x;
        a1 += v.y;
    }
    float nd = norm_dst[wid];
    float o0 = fmaxf(a0 * nd + b1[lane * 2 + 0], 0.f);
    float o1 = fmaxf(a1 * nd + b1[lane * 2 + 1], 0.f);
    *reinterpret_cast<float2*>(&h1[(size_t)wid * F1 + lane * 2]) = make_float2(o0, o1);
}

// ---------------- GEMM2: h2g = (h1 @ W2) * norm_src  [n x 128] @ [128 x 40] ----------------
__global__ __launch_bounds__(256)
void gemm2_kernel(const float* __restrict__ h1, const float* __restrict__ W2,
                  const float* __restrict__ norm_src, float* __restrict__ h2g, int n) {
    __shared__ __align__(16) float W2s[F1][F2];  // 160B pitch, 16B aligned
    for (int i = threadIdx.x; i < F1 * F2; i += 256)
        W2s[i / F2][i % F2] = W2[i];
    __syncthreads();
    int node = blockIdx.x * 256 + threadIdx.x;
    if (node >= n) return;
    float nrm = norm_src[node];
    f32x4 acc4[10] = {};
    const float* row = &h1[(size_t)node * F1];
    for (int k = 0; k < F1; k += 4) {
        float4 a = *reinterpret_cast<const float4*>(&row[k]);
        float av[4] = {a.x, a.y, a.z, a.w};
#pragma unroll
        for (int kk = 0; kk < 4; kk++) {
#pragma unroll
            for (int c4 = 0; c4 < 10; c4++) {
                f32x4 wv = *reinterpret_cast<const f32x4*>(&W2s[k + kk][c4 * 4]);
                acc4[c4] += av[kk] * wv;
            }
        }
    }
    float* orow = &h2g[(size_t)node * F2];
#pragma unroll
    for (int c4 = 0; c4 < 10; c4++) {
        f32x4 o = acc4[c4] * nrm;
        *reinterpret_cast<f32x4*>(&orow[c4 * 4]) = o;
    }
}

// ---------------- Agg2: out = segsum(h2g[src]) * norm_dst + b2, one wave per node ----------------
__global__ __launch_bounds__(256)
void agg2_kernel(const float* __restrict__ h2g, const int* __restrict__ row_off,
                 const int* __restrict__ edge_src, const float* __restrict__ norm_dst,
                 const float* __restrict__ b2, float* __restrict__ out, int n) {
    int wid = (blockIdx.x * blockDim.x + threadIdx.x) >> 6;
    int lane = threadIdx.x & 63;
    if (wid >= n) return;
    int beg = row_off[wid], end = row_off[wid + 1];
    float a0 = 0.f, a1 = 0.f, a2 = 0.f, a3 = 0.f;
    int e = beg;
    for (; e + 3 < end; e += 4) {
        int s0 = edge_src[e + 0];
        int s1 = edge_src[e + 1];
        int s2 = edge_src[e + 2];
        int s3 = edge_src[e + 3];
        if (lane < F2) {
            a0 += h2g[(size_t)s0 * F2 + lane];
            a1 += h2g[(size_t)s1 * F2 + lane];
            a2 += h2g[(size_t)s2 * F2 + lane];
            a3 += h2g[(size_t)s3 * F2 + lane];
        }
    }
    for (; e < end; ++e) {
        int s = edge_src[e];
        if (lane < F2) a0 += h2g[(size_t)s * F2 + lane];
    }
    if (lane < F2) {
        float nd = norm_dst[wid];
        out[(size_t)wid * F2 + lane] = ((a0 + a1) + (a2 + a3)) * nd + b2[lane];
    }
}

extern "C" void kernel_launch(void* const* d_in, const int* in_sizes, int n_in,
                              void* d_out, int out_size, void* d_ws, size_t ws_size,
                              hipStream_t stream) {
    const float* x  = (const float*)d_in[0];
    const float* W1 = (const float*)d_in[1];
    const float* b1 = (const float*)d_in[2];
    const float* W2 = (const float*)d_in[3];
    const float* b2 = (const float*)d_in[4];
    const int* src  = (const int*)d_in[5];
    const int* dst  = (const int*)d_in[6];
    float* out = (float*)d_out;

    const int n = in_sizes[0] / F0;
    const int E = in_sizes[5];
    const int nb = (n + 255) / 256;

    char* ws = (char*)d_ws;
    auto alloc = [&](size_t bytes) -> char* {
        char* p = ws;
        ws += (bytes + 255) & ~(size_t)255;
        return p;
    };
    int* counters  = (int*)alloc((size_t)3 * n * 4);  // deg_src, deg_dst, cursor
    int* deg_src = counters;
    int* deg_dst = counters + n;
    int* cursor  = counters + 2 * n;
    int* row_off   = (int*)alloc((size_t)(n + 1) * 4);
    int* bsum      = (int*)alloc(256 * 4);
    int* edge_srcs = (int*)alloc((size_t)E * 4);
    float* norm_src_d = (float*)alloc((size_t)n * 4);
    float* norm_dst_d = (float*)alloc((size_t)n * 4);
    ushort* W1t_hi = (ushort*)alloc((size_t)F1 * F0 * 2);
    ushort* W1t_lo = (ushort*)alloc((size_t)F1 * F0 * 2);
    float* h1g = (float*)alloc((size_t)n * F1 * 4);
    float* h1  = (float*)alloc((size_t)n * F1 * 4);
    float* h2g = h1g;  // reuse: h1g dead after agg1 (n*F2 <= n*F1)

    zero_i32<<<256, 256, 0, stream>>>(counters, 3 * n);
    degree_kernel<<<2048, 256, 0, stream>>>(src, dst, deg_src, deg_dst, E);
    norm_kernel<<<(n + 255) / 256, 256, 0, stream>>>(deg_src, deg_dst, norm_src_d, norm_dst_d, n);
    scan_block_kernel<<<nb, 256, 0, stream>>>(deg_dst, row_off, bsum, n);
    scan_sums_kernel<<<1, 256, 0, stream>>>(bsum, nb);
    scan_add_kernel<<<256, 256, 0, stream>>>(row_off, bsum, n);
    binning_kernel<<<2048, 256, 0, stream>>>(src, dst, row_off, cursor, edge_srcs, E);
    wconv1_kernel<<<(F0 * F1) / 256, 256, 0, stream>>>(W1, W1t_hi, W1t_lo);
    gemm1_mfma<<<(n + BM - 1) / BM, 256, 0, stream>>>(x, W1t_hi, W1t_lo, norm_src_d, h1g, n);
    agg1_kernel<<<(n + 3) / 4, 256, 0, stream>>>(h1g, row_off, edge_srcs, norm_dst_d, b1, h1, n);
    gemm2_kernel<<<(n + 255) / 256, 256, 0, stream>>>(h1, W2, norm_src_d, h2g, n);
    agg2_kernel<<<(n + 3) / 4, 256, 0, stream>>>(h2g, row_off, edge_srcs, norm_dst_d, b2, out, n);
}

// Round 3
// 276.429 us; speedup vs baseline: 1.8235x; 1.0144x over previous
//
#include <hip/hip_runtime.h>

#define F0 512
#define F1 128
#define F2 40

#define NR 6400     // nodes per histogram partition (LDS ints)
#define G_SL 32     // edge slices

typedef __attribute__((ext_vector_type(8))) short bf16x8;
typedef __attribute__((ext_vector_type(4))) float f32x4;

__device__ inline ushort f2bf(float f) {
    union { float f; uint u; } v; v.f = f;
    uint u = v.u;
    uint r = u + 0x7fffu + ((u >> 16) & 1u);   // RNE
    return (ushort)(r >> 16);
}
__device__ inline float bf2f(ushort h) {
    union { uint u; float f; } v; v.u = ((uint)h) << 16;
    return v.f;
}

// ---------------- graph prep: atomic-free histogram + counting sort ----------------
// Gsrc/Gdst: [G_SL][n] per-slice counts. Block (p,g): LDS histogram of slice g over node range p.
__global__ __launch_bounds__(256)
void hist_kernel(const int* __restrict__ src, const int* __restrict__ dst,
                 int* __restrict__ Gsrc, int* __restrict__ Gdst, int n, int E) {
    __shared__ int cs[NR];
    __shared__ int cd[NR];
    const int p = blockIdx.x / G_SL;
    const int g = blockIdx.x % G_SL;
    const int base = p * NR;
    for (int i = threadIdx.x; i < NR; i += 256) { cs[i] = 0; cd[i] = 0; }
    __syncthreads();
    const int Epg = (E + G_SL - 1) / G_SL;
    const int e0 = g * Epg;
    const int e1 = min(E, e0 + Epg);
    for (int i = e0 + (int)threadIdx.x; i < e1; i += 256) {
        int s = src[i], d = dst[i];
        unsigned so = (unsigned)(s - base);
        unsigned dd = (unsigned)(d - base);
        if (so < (unsigned)NR) atomicAdd(&cs[so], 1);
        if (dd < (unsigned)NR) atomicAdd(&cd[dd], 1);
    }
    __syncthreads();
    const int lim = min(NR, n - base);
    for (int i = threadIdx.x; i < lim; i += 256) {
        Gsrc[(size_t)g * n + base + i] = cs[i];
        Gdst[(size_t)g * n + base + i] = cd[i];
    }
}

__global__ void sumnorm_kernel(const int* __restrict__ Gsrc, const int* __restrict__ Gdst,
                               float* __restrict__ norm_src, float* __restrict__ norm_dst,
                               int* __restrict__ deg_dst, int n) {
    int v = blockIdx.x * blockDim.x + threadIdx.x;
    int stride = gridDim.x * blockDim.x;
    for (; v < n; v += stride) {
        int s = 0, d = 0;
#pragma unroll
        for (int g = 0; g < G_SL; g++) {
            s += Gsrc[(size_t)g * n + v];
            d += Gdst[(size_t)g * n + v];
        }
        norm_src[v] = s > 0 ? rsqrtf((float)s) : 0.f;
        norm_dst[v] = d > 0 ? rsqrtf((float)d) : 0.f;
        deg_dst[v] = d;
    }
}

// ---------------- hierarchical scan (3 kernels) ----------------
__global__ __launch_bounds__(256)
void scan_block_kernel(const int* __restrict__ deg, int* __restrict__ row_off,
                       int* __restrict__ bsum, int n) {
    __shared__ int sm[256];
    int i = blockIdx.x * 256 + threadIdx.x;
    int v = (i < n) ? deg[i] : 0;
    sm[threadIdx.x] = v;
    __syncthreads();
    for (int off = 1; off < 256; off <<= 1) {
        int t = (threadIdx.x >= (unsigned)off) ? sm[threadIdx.x - off] : 0;
        __syncthreads();
        sm[threadIdx.x] += t;
        __syncthreads();
    }
    if (i < n) row_off[i + 1] = sm[threadIdx.x];
    if (threadIdx.x == 255) bsum[blockIdx.x] = sm[255];
}

__global__ __launch_bounds__(256)
void scan_sums_kernel(int* __restrict__ bsum, int nb) {
    __shared__ int sm[256];
    int v = ((int)threadIdx.x < nb) ? bsum[threadIdx.x] : 0;
    sm[threadIdx.x] = v;
    __syncthreads();
    for (int off = 1; off < 256; off <<= 1) {
        int t = (threadIdx.x >= (unsigned)off) ? sm[threadIdx.x - off] : 0;
        __syncthreads();
        sm[threadIdx.x] += t;
        __syncthreads();
    }
    if ((int)threadIdx.x < nb) bsum[threadIdx.x] = sm[threadIdx.x];  // inclusive
}

__global__ void scan_add_kernel(int* __restrict__ row_off, const int* __restrict__ bsum, int n) {
    int i = blockIdx.x * blockDim.x + threadIdx.x;
    int stride = gridDim.x * blockDim.x;
    for (int j = i; j < n; j += stride) {
        int b = j >> 8;
        int add = (b > 0) ? bsum[b - 1] : 0;
        row_off[j + 1] += add;
    }
    if (i == 0) row_off[0] = 0;
}

// transform per-slice counts into per-slice start offsets: Gdst[g][v] = row_off[v] + sum_{g'<g} cnt[g'][v]
__global__ void offs_kernel(int* __restrict__ Gdst, const int* __restrict__ row_off, int n) {
    int v = blockIdx.x * blockDim.x + threadIdx.x;
    int stride = gridDim.x * blockDim.x;
    for (; v < n; v += stride) {
        int run = row_off[v];
#pragma unroll
        for (int g = 0; g < G_SL; g++) {
            int t = Gdst[(size_t)g * n + v];
            Gdst[(size_t)g * n + v] = run;
            run += t;
        }
    }
}

// counting-sort placement: no global atomics (LDS cursors seeded from offsets)
__global__ __launch_bounds__(256)
void place_kernel(const int* __restrict__ src, const int* __restrict__ dst,
                  const int* __restrict__ Gdst, int* __restrict__ edge_src, int n, int E) {
    __shared__ int cur[NR];
    const int p = blockIdx.x / G_SL;
    const int g = blockIdx.x % G_SL;
    const int base = p * NR;
    const int lim = min(NR, n - base);
    for (int i = threadIdx.x; i < lim; i += 256)
        cur[i] = Gdst[(size_t)g * n + base + i];
    __syncthreads();
    const int Epg = (E + G_SL - 1) / G_SL;
    const int e0 = g * Epg;
    const int e1 = min(E, e0 + Epg);
    for (int i = e0 + (int)threadIdx.x; i < e1; i += 256) {
        int d = dst[i];
        unsigned dd = (unsigned)(d - base);
        if (dd < (unsigned)lim) {
            int pos = atomicAdd(&cur[dd], 1);   // LDS atomic
            edge_src[pos] = src[i];
        }
    }
}

// ---------------- W1 preconvert: [512][128] f32 -> hi/lo bf16 transposed [128][512] ----------------
__global__ __launch_bounds__(256)
void wconv1_kernel(const float* __restrict__ W1, ushort* __restrict__ Wt_hi,
                   ushort* __restrict__ Wt_lo) {
    int idx = blockIdx.x * 256 + threadIdx.x;  // 0..65535
    int k = idx >> 7, nn = idx & 127;
    float f = W1[idx];
    ushort h = f2bf(f);
    ushort l = f2bf(f - bf2f(h));
    Wt_hi[nn * F0 + k] = h;
    Wt_lo[nn * F0 + k] = l;
}

// ---------------- GEMM1 (MFMA, split bf16): h1g = (x @ W1) * norm_src ----------------
// BM=64: 4 waves x 16 rows each; full N=128 per wave. A loaded direct from global
// (converted once per element); B staged in LDS (pitch 40 -> 2-way reads, free).
#define BM 64
#define LDB 40
__global__ __launch_bounds__(256)
void gemm1_mfma(const float* __restrict__ x, const ushort* __restrict__ Wt_hi,
                const ushort* __restrict__ Wt_lo, const float* __restrict__ norm_src,
                float* __restrict__ h1g, int n) {
    __shared__ __align__(16) ushort Bhi[F1][LDB];
    __shared__ __align__(16) ushort Blo[F1][LDB];

    const int tid = threadIdx.x;
    const int lane = tid & 63;
    const int w = tid >> 6;           // 0..3: wave's 16-row group
    const int l15 = lane & 15;
    const int lq = lane >> 4;         // 0..3
    const int bm = blockIdx.x * BM;

    const int arow = bm + w * 16 + l15;
    const bool rowok = arow < n;
    const float* xrow = x + (size_t)(rowok ? arow : 0) * F0;

    const int br = tid >> 1;          // 0..127 staging col-row
    const int bk = (tid & 1) * 16;    // 0 / 16 (ushort units)

    f32x4 acc[8] = {};

    uint4 ph0, ph1, pl0, pl1;
    const size_t bbase = (size_t)br * F0 + bk;
    auto loadB = [&](int k0) {
        const uint4* p_hi = reinterpret_cast<const uint4*>(&Wt_hi[bbase + k0]);
        const uint4* p_lo = reinterpret_cast<const uint4*>(&Wt_lo[bbase + k0]);
        ph0 = p_hi[0]; ph1 = p_hi[1];
        pl0 = p_lo[0]; pl1 = p_lo[1];
    };
    auto writeB = [&]() {
        *reinterpret_cast<uint4*>(&Bhi[br][bk + 0]) = ph0;
        *reinterpret_cast<uint4*>(&Bhi[br][bk + 8]) = ph1;
        *reinterpret_cast<uint4*>(&Blo[br][bk + 0]) = pl0;
        *reinterpret_cast<uint4*>(&Blo[br][bk + 8]) = pl1;
    };

    loadB(0);
    writeB();
    __syncthreads();

    for (int kt = 0; kt < 16; kt++) {
        const int k0 = kt * 32;
        if (kt < 15) loadB(k0 + 32);   // issue next-tile global loads early

        // A fragment: direct global load + split-convert (once per element)
        float vv[8];
        if (rowok) {
            float4 p0 = *reinterpret_cast<const float4*>(xrow + k0 + lq * 8);
            float4 p1 = *reinterpret_cast<const float4*>(xrow + k0 + lq * 8 + 4);
            vv[0] = p0.x; vv[1] = p0.y; vv[2] = p0.z; vv[3] = p0.w;
            vv[4] = p1.x; vv[5] = p1.y; vv[6] = p1.z; vv[7] = p1.w;
        } else {
#pragma unroll
            for (int j = 0; j < 8; j++) vv[j] = 0.f;
        }
        ushort hi[8], lo[8];
#pragma unroll
        for (int j = 0; j < 8; j++) {
            hi[j] = f2bf(vv[j]);
            lo[j] = f2bf(vv[j] - bf2f(hi[j]));
        }
        union { ushort us[8]; bf16x8 v; } ua, ul;
#pragma unroll
        for (int j = 0; j < 8; j++) { ua.us[j] = hi[j]; ul.us[j] = lo[j]; }
        bf16x8 a_hi = ua.v, a_lo = ul.v;

#pragma unroll
        for (int ni = 0; ni < 8; ni++) {
            bf16x8 b_hi = *reinterpret_cast<const bf16x8*>(&Bhi[ni * 16 + l15][lq * 8]);
            bf16x8 b_lo = *reinterpret_cast<const bf16x8*>(&Blo[ni * 16 + l15][lq * 8]);
            acc[ni] = __builtin_amdgcn_mfma_f32_16x16x32_bf16(a_hi, b_hi, acc[ni], 0, 0, 0);
            acc[ni] = __builtin_amdgcn_mfma_f32_16x16x32_bf16(a_hi, b_lo, acc[ni], 0, 0, 0);
            acc[ni] = __builtin_amdgcn_mfma_f32_16x16x32_bf16(a_lo, b_hi, acc[ni], 0, 0, 0);
        }

        if (kt < 15) {
            __syncthreads();   // all waves done reading B
            writeB();          // commit next tile
            __syncthreads();   // writes visible
        }
    }

    // epilogue: C layout col=lane&15, row=4*(lane>>4)+reg
#pragma unroll
    for (int r = 0; r < 4; r++) {
        int row = bm + w * 16 + lq * 4 + r;
        if (row < n) {
            float ns = norm_src[row];
#pragma unroll
            for (int ni = 0; ni < 8; ni++) {
                h1g[(size_t)row * F1 + ni * 16 + l15] = acc[ni][r] * ns;
            }
        }
    }
}

// ---------------- Agg1: h1 = relu(segsum(h1g[src]) * norm_dst + b1), one wave per node ----------------
__global__ __launch_bounds__(256)
void agg1_kernel(const float* __restrict__ h1g, const int* __restrict__ row_off,
                 const int* __restrict__ edge_src, const float* __restrict__ norm_dst,
                 const float* __restrict__ b1, float* __restrict__ h1, int n) {
    int wid = (blockIdx.x * blockDim.x + threadIdx.x) >> 6;
    int lane = threadIdx.x & 63;
    if (wid >= n) return;
    int beg = row_off[wid], end = row_off[wid + 1];
    float a0 = 0.f, a1 = 0.f;
    int e = beg;
    for (; e + 3 < end; e += 4) {
        int s0 = edge_src[e + 0];
        int s1 = edge_src[e + 1];
        int s2 = edge_src[e + 2];
        int s3 = edge_src[e + 3];
        float2 v0 = *reinterpret_cast<const float2*>(&h1g[(size_t)s0 * F1 + lane * 2]);
        float2 v1 = *reinterpret_cast<const float2*>(&h1g[(size_t)s1 * F1 + lane * 2]);
        float2 v2 = *reinterpret_cast<const float2*>(&h1g[(size_t)s2 * F1 + lane * 2]);
        float2 v3 = *reinterpret_cast<const float2*>(&h1g[(size_t)s3 * F1 + lane * 2]);
        a0 += (v0.x + v1.x) + (v2.x + v3.x);
        a1 += (v0.y + v1.y) + (v2.y + v3.y);
    }
    for (; e < end; ++e) {
        int s = edge_src[e];
        float2 v = *reinterpret_cast<const float2*>(&h1g[(size_t)s * F1 + lane * 2]);
        a0 += v.x;
        a1 += v.y;
    }
    float nd = norm_dst[wid];
    float o0 = fmaxf(a0 * nd + b1[lane * 2 + 0], 0.f);
    float o1 = fmaxf(a1 * nd + b1[lane * 2 + 1], 0.f);
    *reinterpret_cast<float2*>(&h1[(size_t)wid * F1 + lane * 2]) = make_float2(o0, o1);
}

// ---------------- GEMM2: h2g = (h1 @ W2) * norm_src  [n x 128] @ [128 x 40] ----------------
__global__ __launch_bounds__(256)
void gemm2_kernel(const float* __restrict__ h1, const float* __restrict__ W2,
                  const float* __restrict__ norm_src, float* __restrict__ h2g, int n) {
    __shared__ __align__(16) float W2s[F1][F2];
    for (int i = threadIdx.x; i < F1 * F2; i += 256)
        W2s[i / F2][i % F2] = W2[i];
    __syncthreads();
    int node = blockIdx.x * 256 + threadIdx.x;
    if (node >= n) return;
    float nrm = norm_src[node];
    f32x4 acc4[10] = {};
    const float* row = &h1[(size_t)node * F1];
    for (int k = 0; k < F1; k += 4) {
        float4 a = *reinterpret_cast<const float4*>(&row[k]);
        float av[4] = {a.x, a.y, a.z, a.w};
#pragma unroll
        for (int kk = 0; kk < 4; kk++) {
#pragma unroll
            for (int c4 = 0; c4 < 10; c4++) {
                f32x4 wv = *reinterpret_cast<const f32x4*>(&W2s[k + kk][c4 * 4]);
                acc4[c4] += av[kk] * wv;
            }
        }
    }
    float* orow = &h2g[(size_t)node * F2];
#pragma unroll
    for (int c4 = 0; c4 < 10; c4++) {
        f32x4 o = acc4[c4] * nrm;
        *reinterpret_cast<f32x4*>(&orow[c4 * 4]) = o;
    }
}

// ---------------- Agg2: out = segsum(h2g[src]) * norm_dst + b2, one wave per node ----------------
__global__ __launch_bounds__(256)
void agg2_kernel(const float* __restrict__ h2g, const int* __restrict__ row_off,
                 const int* __restrict__ edge_src, const float* __restrict__ norm_dst,
                 const float* __restrict__ b2, float* __restrict__ out, int n) {
    int wid = (blockIdx.x * blockDim.x + threadIdx.x) >> 6;
    int lane = threadIdx.x & 63;
    if (wid >= n) return;
    int beg = row_off[wid], end = row_off[wid + 1];
    float a0 = 0.f, a1 = 0.f, a2 = 0.f, a3 = 0.f;
    int e = beg;
    for (; e + 3 < end; e += 4) {
        int s0 = edge_src[e + 0];
        int s1 = edge_src[e + 1];
        int s2 = edge_src[e + 2];
        int s3 = edge_src[e + 3];
        if (lane < F2) {
            a0 += h2g[(size_t)s0 * F2 + lane];
            a1 += h2g[(size_t)s1 * F2 + lane];
            a2 += h2g[(size_t)s2 * F2 + lane];
            a3 += h2g[(size_t)s3 * F2 + lane];
        }
    }
    for (; e < end; ++e) {
        int s = edge_src[e];
        if (lane < F2) a0 += h2g[(size_t)s * F2 + lane];
    }
    if (lane < F2) {
        float nd = norm_dst[wid];
        out[(size_t)wid * F2 + lane] = ((a0 + a1) + (a2 + a3)) * nd + b2[lane];
    }
}

extern "C" void kernel_launch(void* const* d_in, const int* in_sizes, int n_in,
                              void* d_out, int out_size, void* d_ws, size_t ws_size,
                              hipStream_t stream) {
    const float* x  = (const float*)d_in[0];
    const float* W1 = (const float*)d_in[1];
    const float* b1 = (const float*)d_in[2];
    const float* W2 = (const float*)d_in[3];
    const float* b2 = (const float*)d_in[4];
    const int* src  = (const int*)d_in[5];
    const int* dst  = (const int*)d_in[6];
    float* out = (float*)d_out;

    const int n = in_sizes[0] / F0;
    const int E = in_sizes[5];
    const int nb = (n + 255) / 256;
    const int P = (n + NR - 1) / NR;

    char* ws = (char*)d_ws;
    auto alloc = [&](size_t bytes) -> char* {
        char* p = ws;
        ws += (bytes + 255) & ~(size_t)255;
        return p;
    };
    int* deg_dst   = (int*)alloc((size_t)n * 4);
    int* row_off   = (int*)alloc((size_t)(n + 1) * 4);
    int* bsum      = (int*)alloc(256 * 4);
    int* edge_srcs = (int*)alloc((size_t)E * 4);
    float* norm_src_d = (float*)alloc((size_t)n * 4);
    float* norm_dst_d = (float*)alloc((size_t)n * 4);
    ushort* W1t_hi = (ushort*)alloc((size_t)F1 * F0 * 2);
    ushort* W1t_lo = (ushort*)alloc((size_t)F1 * F0 * 2);
    float* h1g = (float*)alloc((size_t)n * F1 * 4);
    float* h1  = (float*)alloc((size_t)n * F1 * 4);
    float* h2g = h1g;  // h1g dead after agg1

    // per-slice count arrays alias the (not-yet-live) h1g buffer: 2 * G_SL*n ints <= n*F1 floats
    int* Gsrc = (int*)h1g;
    int* Gdst = Gsrc + (size_t)G_SL * n;

    hist_kernel<<<P * G_SL, 256, 0, stream>>>(src, dst, Gsrc, Gdst, n, E);
    sumnorm_kernel<<<(n + 255) / 256, 256, 0, stream>>>(Gsrc, Gdst, norm_src_d, norm_dst_d, deg_dst, n);
    scan_block_kernel<<<nb, 256, 0, stream>>>(deg_dst, row_off, bsum, n);
    scan_sums_kernel<<<1, 256, 0, stream>>>(bsum, nb);
    scan_add_kernel<<<256, 256, 0, stream>>>(row_off, bsum, n);
    offs_kernel<<<(n + 255) / 256, 256, 0, stream>>>(Gdst, row_off, n);
    place_kernel<<<P * G_SL, 256, 0, stream>>>(src, dst, Gdst, edge_srcs, n, E);
    wconv1_kernel<<<(F0 * F1) / 256, 256, 0, stream>>>(W1, W1t_hi, W1t_lo);
    gemm1_mfma<<<(n + BM - 1) / BM, 256, 0, stream>>>(x, W1t_hi, W1t_lo, norm_src_d, h1g, n);
    agg1_kernel<<<(n + 3) / 4, 256, 0, stream>>>(h1g, row_off, edge_srcs, norm_dst_d, b1, h1, n);
    gemm2_kernel<<<(n + 255) / 256, 256, 0, stream>>>(h1, W2, norm_src_d, h2g, n);
    agg2_kernel<<<(n + 3) / 4, 256, 0, stream>>>(h2g, row_off, edge_srcs, norm_dst_d, b2, out, n);
}

// Round 4
// 274.513 us; speedup vs baseline: 1.8362x; 1.0070x over previous
//
#include <hip/hip_runtime.h>
#include <hip/hip_bf16.h>

#define F0 512
#define F1 128
#define F2 40

#define NRP 12800   // nodes per histogram partition (packed ushort counters, 25.6KB LDS/array)
#define G_SL 32     // edge slices

typedef __attribute__((ext_vector_type(8))) short bf16x8;
typedef __attribute__((ext_vector_type(4))) float f32x4;

__device__ inline ushort f2bf(float f) {
    union { float f; uint u; } v; v.f = f;
    uint u = v.u;
    uint r = u + 0x7fffu + ((u >> 16) & 1u);   // RNE
    return (ushort)(r >> 16);
}
__device__ inline float bf2f(ushort h) {
    union { uint u; float f; } v; v.u = ((uint)h) << 16;
    return v.f;
}

// ---------------- pass 1: per-slice histograms (packed ushort in LDS, no global atomics) ----------------
__global__ __launch_bounds__(256)
void hist_kernel(const int* __restrict__ src, const int* __restrict__ dst,
                 int* __restrict__ Gsrc, int* __restrict__ Gdst, int n, int E) {
    __shared__ uint cs[NRP / 2];
    __shared__ uint cd[NRP / 2];
    const int p = blockIdx.x / G_SL;
    const int g = blockIdx.x % G_SL;
    const int base = p * NRP;
    for (int i = threadIdx.x; i < NRP / 2; i += 256) { cs[i] = 0; cd[i] = 0; }
    __syncthreads();
    const int Epg = (E + G_SL - 1) / G_SL;
    const int e0 = g * Epg;
    const int e1 = min(E, e0 + Epg);
    for (int i = e0 + (int)threadIdx.x; i < e1; i += 256) {
        int s = src[i], d = dst[i];
        unsigned so = (unsigned)(s - base);
        unsigned dd = (unsigned)(d - base);
        if (so < (unsigned)NRP) atomicAdd(&cs[so >> 1], 1u << ((so & 1) * 16));
        if (dd < (unsigned)NRP) atomicAdd(&cd[dd >> 1], 1u << ((dd & 1) * 16));
    }
    __syncthreads();
    const int lim = min(NRP, n - base);
    for (int i = threadIdx.x; i < lim; i += 256) {
        uint pcs = cs[i >> 1], pcd = cd[i >> 1];
        int sh = (i & 1) * 16;
        Gsrc[(size_t)g * n + base + i] = (int)((pcs >> sh) & 0xffffu);
        Gdst[(size_t)g * n + base + i] = (int)((pcd >> sh) & 0xffffu);
    }
}

// ---------------- pass 2: degree sums + norms + per-256-block inclusive scan ----------------
__global__ __launch_bounds__(256)
void scanA_kernel(const int* __restrict__ Gsrc, const int* __restrict__ Gdst,
                  float* __restrict__ norm_src, float* __restrict__ norm_dst,
                  int* __restrict__ row_off, int* __restrict__ bsum, int n) {
    __shared__ int sm[256];
    int i = blockIdx.x * 256 + threadIdx.x;
    int s = 0, d = 0;
    if (i < n) {
#pragma unroll
        for (int g = 0; g < G_SL; g++) {
            s += Gsrc[(size_t)g * n + i];
            d += Gdst[(size_t)g * n + i];
        }
        norm_src[i] = s > 0 ? rsqrtf((float)s) : 0.f;
        norm_dst[i] = d > 0 ? rsqrtf((float)d) : 0.f;
    }
    sm[threadIdx.x] = (i < n) ? d : 0;
    __syncthreads();
    for (int off = 1; off < 256; off <<= 1) {
        int t = (threadIdx.x >= (unsigned)off) ? sm[threadIdx.x - off] : 0;
        __syncthreads();
        sm[threadIdx.x] += t;
        __syncthreads();
    }
    if (i < n) row_off[i + 1] = sm[threadIdx.x];   // raw: in-block inclusive
    if (threadIdx.x == 255) bsum[blockIdx.x] = sm[255];
}

// ---------------- pass 3: finalize row_off (global exclusive) + per-slice start offsets ----------------
__global__ __launch_bounds__(256)
void finalize_kernel(int* __restrict__ row_off, const int* __restrict__ bsum,
                     int* __restrict__ Gdst, int n) {
    __shared__ int sm[256];
    const int b = blockIdx.x;
    const int t = threadIdx.x;
    sm[t] = (t < b) ? bsum[t] : 0;
    __syncthreads();
#pragma unroll
    for (int off = 128; off > 0; off >>= 1) {
        if (t < off) sm[t] += sm[t + off];
        __syncthreads();
    }
    const int excl = sm[0];
    const int v = b * 256 + t;
    if (v >= n) return;
    int raw = row_off[v];                       // each index read only by its own thread
    int start = excl + ((t == 0) ? 0 : raw);
    if (v == n - 1) {
        int rawn = row_off[n];                  // in-block inclusive through n-1
        row_off[n] = excl + rawn;
    }
    row_off[v] = start;
    int run = start;
#pragma unroll
    for (int g = 0; g < G_SL; g++) {
        size_t idx = (size_t)g * n + v;
        int c = Gdst[idx];
        Gdst[idx] = run;
        run += c;
    }
}

// ---------------- edge placement (counting sort, LDS packed delta cursors) ----------------
__global__ __launch_bounds__(256)
void place_kernel(const int* __restrict__ src, const int* __restrict__ dst,
                  const int* __restrict__ Gdst, int* __restrict__ edge_src, int n, int E) {
    __shared__ uint cur[NRP / 2];
    const int p = blockIdx.x / G_SL;
    const int g = blockIdx.x % G_SL;
    const int base = p * NRP;
    for (int i = threadIdx.x; i < NRP / 2; i += 256) cur[i] = 0;
    __syncthreads();
    const int Epg = (E + G_SL - 1) / G_SL;
    const int e0 = g * Epg;
    const int e1 = min(E, e0 + Epg);
    for (int i = e0 + (int)threadIdx.x; i < e1; i += 256) {
        int d = dst[i];
        unsigned dd = (unsigned)(d - base);
        if (dd < (unsigned)NRP) {
            int sh = (dd & 1) * 16;
            uint old = atomicAdd(&cur[dd >> 1], 1u << sh);
            int delta = (int)((old >> sh) & 0xffffu);
            int pos = Gdst[(size_t)g * n + d] + delta;
            edge_src[pos] = src[i];
        }
    }
}

// ---------------- W1 preconvert: [512][128] f32 -> hi/lo bf16 transposed [128][512] ----------------
__global__ __launch_bounds__(256)
void wconv1_kernel(const float* __restrict__ W1, ushort* __restrict__ Wt_hi,
                   ushort* __restrict__ Wt_lo) {
    int idx = blockIdx.x * 256 + threadIdx.x;  // 0..65535
    int k = idx >> 7, nn = idx & 127;
    float f = W1[idx];
    ushort h = f2bf(f);
    ushort l = f2bf(f - bf2f(h));
    Wt_hi[nn * F0 + k] = h;
    Wt_lo[nn * F0 + k] = l;
}

// ---------------- GEMM1 (MFMA, split bf16): h1g(bf16) = (x @ W1) * norm_src ----------------
// Wave-tile 64x32: each wave computes ALL 64 rows x its 32 cols. A staged in LDS
// (fragment-linear = conflict-free, double-buffered, 1 barrier/iter); B per-lane direct from L2.
#define BM 64
__global__ __launch_bounds__(256)
void gemm1_mfma(const float* __restrict__ x, const ushort* __restrict__ Wt_hi,
                const ushort* __restrict__ Wt_lo, const float* __restrict__ norm_src,
                ushort* __restrict__ h1g, int n) {
    __shared__ __align__(16) ushort Al[2][2][4][64][8];   // [buf][hi/lo][mi][lane][8] = 16KB

    const int tid = threadIdx.x;
    const int lane = tid & 63;
    const int w = tid >> 6;
    const int l15 = lane & 15;
    const int lq = lane >> 4;
    const int bm = blockIdx.x * BM;

    const int ar = tid >> 2;          // staging row 0..63
    const int alq = tid & 3;          // staging k-chunk (8 floats)
    const int smi = ar >> 4;
    const int slane = alq * 16 + (ar & 15);
    const int grow = bm + ar;
    const bool arok = grow < n;
    const float* xrow = x + (size_t)(arok ? grow : 0) * F0;

    const size_t bgoff0 = (size_t)((w * 2 + 0) * 16 + l15) * F0 + lq * 8;
    const size_t bgoff1 = (size_t)((w * 2 + 1) * 16 + l15) * F0 + lq * 8;

    f32x4 acc[4][2] = {};
    float4 a0, a1;
    bf16x8 bhA[2], blA[2], bhB[2], blB[2];

    auto loadA = [&](int k0) {
        if (arok) {
            a0 = *reinterpret_cast<const float4*>(xrow + k0 + alq * 8);
            a1 = *reinterpret_cast<const float4*>(xrow + k0 + alq * 8 + 4);
        } else {
            a0 = make_float4(0.f, 0.f, 0.f, 0.f);
            a1 = a0;
        }
    };
    auto loadB = [&](int k0, bf16x8 (&bh)[2], bf16x8 (&bl)[2]) {
        bh[0] = *reinterpret_cast<const bf16x8*>(Wt_hi + bgoff0 + k0);
        bh[1] = *reinterpret_cast<const bf16x8*>(Wt_hi + bgoff1 + k0);
        bl[0] = *reinterpret_cast<const bf16x8*>(Wt_lo + bgoff0 + k0);
        bl[1] = *reinterpret_cast<const bf16x8*>(Wt_lo + bgoff1 + k0);
    };
    auto stageA = [&](int buf, float4 c0, float4 c1) {
        float cf[8] = {c0.x, c0.y, c0.z, c0.w, c1.x, c1.y, c1.z, c1.w};
        uint hu[4], lu[4];
#pragma unroll
        for (int j = 0; j < 4; j++) {
            float fa = cf[2 * j], fb = cf[2 * j + 1];
            __hip_bfloat162 h2 = __float22bfloat162_rn(make_float2(fa, fb));
            uint h; __builtin_memcpy(&h, &h2, 4);
            float ra = __uint_as_float(h << 16);
            float rb = __uint_as_float(h & 0xffff0000u);
            __hip_bfloat162 l2 = __float22bfloat162_rn(make_float2(fa - ra, fb - rb));
            uint l; __builtin_memcpy(&l, &l2, 4);
            hu[j] = h; lu[j] = l;
        }
        *reinterpret_cast<uint4*>(&Al[buf][0][smi][slane][0]) = make_uint4(hu[0], hu[1], hu[2], hu[3]);
        *reinterpret_cast<uint4*>(&Al[buf][1][smi][slane][0]) = make_uint4(lu[0], lu[1], lu[2], lu[3]);
    };
    auto compute = [&](int buf, bf16x8 (&bh)[2], bf16x8 (&bl)[2]) {
        bf16x8 ah[4], al[4];
#pragma unroll
        for (int mi = 0; mi < 4; mi++) {
            ah[mi] = *reinterpret_cast<const bf16x8*>(&Al[buf][0][mi][lane][0]);
            al[mi] = *reinterpret_cast<const bf16x8*>(&Al[buf][1][mi][lane][0]);
        }
#pragma unroll
        for (int mi = 0; mi < 4; mi++) {
#pragma unroll
            for (int ni = 0; ni < 2; ni++) {
                acc[mi][ni] = __builtin_amdgcn_mfma_f32_16x16x32_bf16(ah[mi], bh[ni], acc[mi][ni], 0, 0, 0);
                acc[mi][ni] = __builtin_amdgcn_mfma_f32_16x16x32_bf16(ah[mi], bl[ni], acc[mi][ni], 0, 0, 0);
                acc[mi][ni] = __builtin_amdgcn_mfma_f32_16x16x32_bf16(al[mi], bh[ni], acc[mi][ni], 0, 0, 0);
            }
        }
    };

    loadA(0);
    {
        float4 c0 = a0, c1 = a1;
        loadA(32);
        loadB(0, bhA, blA);
        stageA(0, c0, c1);
    }
    __syncthreads();

    for (int kt2 = 0; kt2 < 8; kt2++) {
        const int kt = kt2 * 2;
        {   // even iter kt: LDS buf0, B set A
            float4 c0 = a0, c1 = a1;                    // raw A(kt+1)
            if (kt < 14) loadA((kt + 2) * 32);
            loadB((kt + 1) * 32, bhB, blB);             // B(kt+1)
            compute(0, bhA, blA);
            stageA(1, c0, c1);                          // A(kt+1) -> buf1
            __syncthreads();
        }
        {   // odd iter ko: LDS buf1, B set B
            const int ko = kt + 1;
            float4 c0 = a0, c1 = a1;                    // raw A(ko+1)
            if (ko < 14) loadA((ko + 2) * 32);
            if (ko < 15) loadB((ko + 1) * 32, bhA, blA);
            compute(1, bhB, blB);
            if (ko < 15) {
                stageA(0, c0, c1);
                __syncthreads();
            }
        }
    }

#pragma unroll
    for (int mi = 0; mi < 4; mi++) {
        int rbase = bm + mi * 16 + lq * 4;
#pragma unroll
        for (int r = 0; r < 4; r++) {
            int row = rbase + r;
            if (row < n) {
                float ns = norm_src[row];
#pragma unroll
                for (int ni = 0; ni < 2; ni++) {
                    h1g[(size_t)row * F1 + (w * 2 + ni) * 16 + l15] = f2bf(acc[mi][ni][r] * ns);
                }
            }
        }
    }
}

// ---------------- Agg1: h1 = relu(segsum(h1g[src]) * norm_dst + b1), one wave per node ----------------
__global__ __launch_bounds__(256)
void agg1_kernel(const ushort* __restrict__ h1g, const int* __restrict__ row_off,
                 const int* __restrict__ edge_src, const float* __restrict__ norm_dst,
                 const float* __restrict__ b1, float* __restrict__ h1, int n) {
    int wid = (blockIdx.x * blockDim.x + threadIdx.x) >> 6;
    int lane = threadIdx.x & 63;
    if (wid >= n) return;
    int beg = row_off[wid], end = row_off[wid + 1];
    float a0 = 0.f, a1 = 0.f;
    int e = beg;
    for (; e + 3 < end; e += 4) {
        int s0 = edge_src[e + 0];
        int s1 = edge_src[e + 1];
        int s2 = edge_src[e + 2];
        int s3 = edge_src[e + 3];
        uint v0 = *reinterpret_cast<const uint*>(&h1g[(size_t)s0 * F1 + lane * 2]);
        uint v1 = *reinterpret_cast<const uint*>(&h1g[(size_t)s1 * F1 + lane * 2]);
        uint v2 = *reinterpret_cast<const uint*>(&h1g[(size_t)s2 * F1 + lane * 2]);
        uint v3 = *reinterpret_cast<const uint*>(&h1g[(size_t)s3 * F1 + lane * 2]);
        a0 += (__uint_as_float(v0 << 16) + __uint_as_float(v1 << 16)) +
              (__uint_as_float(v2 << 16) + __uint_as_float(v3 << 16));
        a1 += (__uint_as_float(v0 & 0xffff0000u) + __uint_as_float(v1 & 0xffff0000u)) +
              (__uint_as_float(v2 & 0xffff0000u) + __uint_as_float(v3 & 0xffff0000u));
    }
    for (; e < end; ++e) {
        int s = edge_src[e];
        uint v = *reinterpret_cast<const uint*>(&h1g[(size_t)s * F1 + lane * 2]);
        a0 += __uint_as_float(v << 16);
        a1 += __uint_as_float(v & 0xffff0000u);
    }
    float nd = norm_dst[wid];
    float o0 = fmaxf(a0 * nd + b1[lane * 2 + 0], 0.f);
    float o1 = fmaxf(a1 * nd + b1[lane * 2 + 1], 0.f);
    *reinterpret_cast<float2*>(&h1[(size_t)wid * F1 + lane * 2]) = make_float2(o0, o1);
}

// ---------------- GEMM2: h2g = (h1 @ W2) * norm_src  [n x 128] @ [128 x 40] ----------------
__global__ __launch_bounds__(256)
void gemm2_kernel(const float* __restrict__ h1, const float* __restrict__ W2,
                  const float* __restrict__ norm_src, float* __restrict__ h2g, int n) {
    __shared__ __align__(16) float W2s[F1][F2];
    for (int i = threadIdx.x; i < F1 * F2; i += 256)
        W2s[i / F2][i % F2] = W2[i];
    __syncthreads();
    int node = blockIdx.x * 256 + threadIdx.x;
    if (node >= n) return;
    float nrm = norm_src[node];
    f32x4 acc4[10] = {};
    const float* row = &h1[(size_t)node * F1];
    for (int k = 0; k < F1; k += 4) {
        float4 a = *reinterpret_cast<const float4*>(&row[k]);
        float av[4] = {a.x, a.y, a.z, a.w};
#pragma unroll
        for (int kk = 0; kk < 4; kk++) {
#pragma unroll
            for (int c4 = 0; c4 < 10; c4++) {
                f32x4 wv = *reinterpret_cast<const f32x4*>(&W2s[k + kk][c4 * 4]);
                acc4[c4] += av[kk] * wv;
            }
        }
    }
    float* orow = &h2g[(size_t)node * F2];
#pragma unroll
    for (int c4 = 0; c4 < 10; c4++) {
        f32x4 o = acc4[c4] * nrm;
        *reinterpret_cast<f32x4*>(&orow[c4 * 4]) = o;
    }
}

// ---------------- Agg2: out = segsum(h2g[src]) * norm_dst + b2, one wave per node ----------------
__global__ __launch_bounds__(256)
void agg2_kernel(const float* __restrict__ h2g, const int* __restrict__ row_off,
                 const int* __restrict__ edge_src, const float* __restrict__ norm_dst,
                 const float* __restrict__ b2, float* __restrict__ out, int n) {
    int wid = (blockIdx.x * blockDim.x + threadIdx.x) >> 6;
    int lane = threadIdx.x & 63;
    if (wid >= n) return;
    int beg = row_off[wid], end = row_off[wid + 1];
    float a0 = 0.f, a1 = 0.f, a2 = 0.f, a3 = 0.f;
    int e = beg;
    for (; e + 3 < end; e += 4) {
        int s0 = edge_src[e + 0];
        int s1 = edge_src[e + 1];
        int s2 = edge_src[e + 2];
        int s3 = edge_src[e + 3];
        if (lane < F2) {
            a0 += h2g[(size_t)s0 * F2 + lane];
            a1 += h2g[(size_t)s1 * F2 + lane];
            a2 += h2g[(size_t)s2 * F2 + lane];
            a3 += h2g[(size_t)s3 * F2 + lane];
        }
    }
    for (; e < end; ++e) {
        int s = edge_src[e];
        if (lane < F2) a0 += h2g[(size_t)s * F2 + lane];
    }
    if (lane < F2) {
        float nd = norm_dst[wid];
        out[(size_t)wid * F2 + lane] = ((a0 + a1) + (a2 + a3)) * nd + b2[lane];
    }
}

extern "C" void kernel_launch(void* const* d_in, const int* in_sizes, int n_in,
                              void* d_out, int out_size, void* d_ws, size_t ws_size,
                              hipStream_t stream) {
    const float* x  = (const float*)d_in[0];
    const float* W1 = (const float*)d_in[1];
    const float* b1 = (const float*)d_in[2];
    const float* W2 = (const float*)d_in[3];
    const float* b2 = (const float*)d_in[4];
    const int* src  = (const int*)d_in[5];
    const int* dst  = (const int*)d_in[6];
    float* out = (float*)d_out;

    const int n = in_sizes[0] / F0;
    const int E = in_sizes[5];
    const int nb = (n + 255) / 256;
    const int P = (n + NRP - 1) / NRP;

    char* ws = (char*)d_ws;
    auto alloc = [&](size_t bytes) -> char* {
        char* p = ws;
        ws += (bytes + 255) & ~(size_t)255;
        return p;
    };
    int* row_off   = (int*)alloc((size_t)(n + 1) * 4);
    int* bsum      = (int*)alloc(256 * 4);
    int* edge_srcs = (int*)alloc((size_t)E * 4);
    float* norm_src_d = (float*)alloc((size_t)n * 4);
    float* norm_dst_d = (float*)alloc((size_t)n * 4);
    ushort* W1t_hi = (ushort*)alloc((size_t)F1 * F0 * 2);
    ushort* W1t_lo = (ushort*)alloc((size_t)F1 * F0 * 2);
    ushort* h1g = (ushort*)alloc((size_t)n * F1 * 2);   // bf16
    float* h1  = (float*)alloc((size_t)n * F1 * 4);
    float* h2g = (float*)h1g;   // reuse after agg1: n*F2*4 (8MB) <= n*F1*2 (12.8MB)

    // per-slice count/offset arrays alias h1g (not yet live): 2 * G_SL * n ints = n*F1*2 bytes
    int* Gsrc = (int*)h1g;
    int* Gdst = Gsrc + (size_t)G_SL * n;

    hist_kernel<<<P * G_SL, 256, 0, stream>>>(src, dst, Gsrc, Gdst, n, E);
    scanA_kernel<<<nb, 256, 0, stream>>>(Gsrc, Gdst, norm_src_d, norm_dst_d, row_off, bsum, n);
    finalize_kernel<<<nb, 256, 0, stream>>>(row_off, bsum, Gdst, n);
    place_kernel<<<P * G_SL, 256, 0, stream>>>(src, dst, Gdst, edge_srcs, n, E);
    wconv1_kernel<<<(F0 * F1) / 256, 256, 0, stream>>>(W1, W1t_hi, W1t_lo);
    gemm1_mfma<<<(n + BM - 1) / BM, 256, 0, stream>>>(x, W1t_hi, W1t_lo, norm_src_d, h1g, n);
    agg1_kernel<<<(n + 3) / 4, 256, 0, stream>>>(h1g, row_off, edge_srcs, norm_dst_d, b1, h1, n);
    gemm2_kernel<<<(n + 255) / 256, 256, 0, stream>>>(h1, W2, norm_src_d, h2g, n);
    agg2_kernel<<<(n + 3) / 4, 256, 0, stream>>>(h2g, row_off, edge_srcs, norm_dst_d, b2, out, n);
}

// Round 5
// 255.594 us; speedup vs baseline: 1.9721x; 1.0740x over previous
//
#include <hip/hip_runtime.h>
#include <hip/hip_bf16.h>

#define F0 512
#define F1 128
#define F2 40

#define NRP 12800   // nodes per histogram partition (packed ushort counters)
#define G_SL 32     // edge slices

typedef __attribute__((ext_vector_type(8))) short bf16x8;
typedef __attribute__((ext_vector_type(4))) float f32x4;

__device__ inline ushort f2bf(float f) {
    union { float f; uint u; } v; v.f = f;
    uint u = v.u;
    uint r = u + 0x7fffu + ((u >> 16) & 1u);   // RNE
    return (ushort)(r >> 16);
}
__device__ inline float bf2f(ushort h) {
    union { uint u; float f; } v; v.u = ((uint)h) << 16;
    return v.f;
}

// ---------------- pass 1: per-slice histograms (packed ushort in LDS, no global atomics) ----------------
__global__ __launch_bounds__(256)
void hist_kernel(const int* __restrict__ src, const int* __restrict__ dst,
                 int* __restrict__ Gsrc, int* __restrict__ Gdst, int n, int E) {
    __shared__ uint cs[NRP / 2];
    __shared__ uint cd[NRP / 2];
    const int p = blockIdx.x / G_SL;
    const int g = blockIdx.x % G_SL;
    const int base = p * NRP;
    for (int i = threadIdx.x; i < NRP / 2; i += 256) { cs[i] = 0; cd[i] = 0; }
    __syncthreads();
    const int Epg = (E + G_SL - 1) / G_SL;
    const int e0 = g * Epg;
    const int e1 = min(E, e0 + Epg);
    for (int i = e0 + (int)threadIdx.x; i < e1; i += 256) {
        int s = src[i], d = dst[i];
        unsigned so = (unsigned)(s - base);
        unsigned dd = (unsigned)(d - base);
        if (so < (unsigned)NRP) atomicAdd(&cs[so >> 1], 1u << ((so & 1) * 16));
        if (dd < (unsigned)NRP) atomicAdd(&cd[dd >> 1], 1u << ((dd & 1) * 16));
    }
    __syncthreads();
    const int lim = min(NRP, n - base);
    for (int i = threadIdx.x; i < lim; i += 256) {
        uint pcs = cs[i >> 1], pcd = cd[i >> 1];
        int sh = (i & 1) * 16;
        Gsrc[(size_t)g * n + base + i] = (int)((pcs >> sh) & 0xffffu);
        Gdst[(size_t)g * n + base + i] = (int)((pcd >> sh) & 0xffffu);
    }
}

// ---------------- pass 2: degree sums + norms + per-256-block inclusive scan ----------------
__global__ __launch_bounds__(256)
void scanA_kernel(const int* __restrict__ Gsrc, const int* __restrict__ Gdst,
                  float* __restrict__ norm_src, float* __restrict__ norm_dst,
                  int* __restrict__ row_off, int* __restrict__ bsum, int n) {
    __shared__ int sm[256];
    int i = blockIdx.x * 256 + threadIdx.x;
    int s = 0, d = 0;
    if (i < n) {
#pragma unroll
        for (int g = 0; g < G_SL; g++) {
            s += Gsrc[(size_t)g * n + i];
            d += Gdst[(size_t)g * n + i];
        }
        norm_src[i] = s > 0 ? rsqrtf((float)s) : 0.f;
        norm_dst[i] = d > 0 ? rsqrtf((float)d) : 0.f;
    }
    sm[threadIdx.x] = (i < n) ? d : 0;
    __syncthreads();
    for (int off = 1; off < 256; off <<= 1) {
        int t = (threadIdx.x >= (unsigned)off) ? sm[threadIdx.x - off] : 0;
        __syncthreads();
        sm[threadIdx.x] += t;
        __syncthreads();
    }
    if (i < n) row_off[i + 1] = sm[threadIdx.x];   // raw: in-block inclusive
    if (threadIdx.x == 255) bsum[blockIdx.x] = sm[255];
}

// ---------------- pass 3: finalize row_off (global exclusive) + per-slice start offsets ----------------
__global__ __launch_bounds__(256)
void finalize_kernel(int* __restrict__ row_off, const int* __restrict__ bsum,
                     int* __restrict__ Gdst, int n) {
    __shared__ int sm[256];
    const int b = blockIdx.x;
    const int t = threadIdx.x;
    sm[t] = (t < b) ? bsum[t] : 0;
    __syncthreads();
#pragma unroll
    for (int off = 128; off > 0; off >>= 1) {
        if (t < off) sm[t] += sm[t + off];
        __syncthreads();
    }
    const int excl = sm[0];
    const int v = b * 256 + t;
    if (v >= n) return;
    int raw = row_off[v];                       // each index touched only by its own thread
    int start = excl + ((t == 0) ? 0 : raw);
    if (v == n - 1) {
        int rawn = row_off[n];
        row_off[n] = excl + rawn;
    }
    row_off[v] = start;
    int run = start;
#pragma unroll
    for (int g = 0; g < G_SL; g++) {
        size_t idx = (size_t)g * n + v;
        int c = Gdst[idx];
        Gdst[idx] = run;
        run += c;
    }
}

// ---------------- edge placement (counting sort, LDS packed delta cursors) ----------------
__global__ __launch_bounds__(256)
void place_kernel(const int* __restrict__ src, const int* __restrict__ dst,
                  const int* __restrict__ Gdst, int* __restrict__ edge_src, int n, int E) {
    __shared__ uint cur[NRP / 2];
    const int p = blockIdx.x / G_SL;
    const int g = blockIdx.x % G_SL;
    const int base = p * NRP;
    for (int i = threadIdx.x; i < NRP / 2; i += 256) cur[i] = 0;
    __syncthreads();
    const int Epg = (E + G_SL - 1) / G_SL;
    const int e0 = g * Epg;
    const int e1 = min(E, e0 + Epg);
    for (int i = e0 + (int)threadIdx.x; i < e1; i += 256) {
        int d = dst[i];
        unsigned dd = (unsigned)(d - base);
        if (dd < (unsigned)NRP) {
            int sh = (dd & 1) * 16;
            uint old = atomicAdd(&cur[dd >> 1], 1u << sh);
            int delta = (int)((old >> sh) & 0xffffu);
            int pos = Gdst[(size_t)g * n + d] + delta;
            edge_src[pos] = src[i];
        }
    }
}

// ---------------- W1 preconvert: [512][128] f32 -> bf16 transposed [128][512] ----------------
__global__ __launch_bounds__(256)
void wconv1_kernel(const float* __restrict__ W1, ushort* __restrict__ Wt_hi) {
    int idx = blockIdx.x * 256 + threadIdx.x;  // 0..65535
    int k = idx >> 7, nn = idx & 127;
    Wt_hi[nn * F0 + k] = f2bf(W1[idx]);
}

// ---------------- GEMM1 (MFMA, split-A bf16): h1g(bf16) = (x @ W1) * norm_src ----------------
// BM=64, BK=32. Wave w owns cols [w*32, w*32+32) x all 64 rows. A staged in LDS in
// fragment-linear layout: thread t stages frag (mi=t>>6, lane=t&63) -> both ds_write_b128
// and ds_read_b128 are lane-consecutive 16B (minimal 2-way, conflict-free). B (bf16 W1t,
// 128KB, L2-hot) loaded per-lane direct from global, prefetched one k-tile ahead.
#define BM 64
__global__ __launch_bounds__(256)
void gemm1_mfma(const float* __restrict__ x, const ushort* __restrict__ Wt_hi,
                const float* __restrict__ norm_src, ushort* __restrict__ h1g, int n) {
    __shared__ __align__(16) ushort Al[2][4][2][64][8];   // [buf][mi][hi/lo][flane][8] = 16KB

    const int tid = threadIdx.x;
    const int lane = tid & 63;
    const int w = tid >> 6;
    const int l15 = lane & 15;
    const int lq = lane >> 4;
    const int bm = blockIdx.x * BM;

    // A staging: thread t -> fragment (mi = t>>6, flane = t&63)
    const int smi = tid >> 6;
    const int sflane = tid & 63;
    const int srow = smi * 16 + (tid & 15);   // row within tile that frag-lane needs
    const int skc = (tid >> 4) & 3;           // k-chunk (8 floats)
    const int grow = bm + srow;
    const bool arok = grow < n;
    const float* xrow = x + (size_t)(arok ? grow : 0) * F0 + skc * 8;

    // B fragments: wave w covers ni = 2w, 2w+1
    const size_t bgoff0 = (size_t)((w * 2 + 0) * 16 + l15) * F0 + lq * 8;
    const size_t bgoff1 = (size_t)((w * 2 + 1) * 16 + l15) * F0 + lq * 8;

    f32x4 acc[4][2] = {};
    float4 a0, a1;
    bf16x8 bcur0, bcur1, bnxt0, bnxt1;

    auto loadA = [&](int k0) {
        if (arok) {
            a0 = *reinterpret_cast<const float4*>(xrow + k0);
            a1 = *reinterpret_cast<const float4*>(xrow + k0 + 4);
        } else {
            a0 = make_float4(0.f, 0.f, 0.f, 0.f);
            a1 = a0;
        }
    };
    auto stageA = [&](int buf) {
        float cf[8] = {a0.x, a0.y, a0.z, a0.w, a1.x, a1.y, a1.z, a1.w};
        uint hu[4], lu[4];
#pragma unroll
        for (int j = 0; j < 4; j++) {
            float fa = cf[2 * j], fb = cf[2 * j + 1];
            __hip_bfloat162 h2 = __float22bfloat162_rn(make_float2(fa, fb));
            uint h; __builtin_memcpy(&h, &h2, 4);
            float ra = __uint_as_float(h << 16);
            float rb = __uint_as_float(h & 0xffff0000u);
            __hip_bfloat162 l2 = __float22bfloat162_rn(make_float2(fa - ra, fb - rb));
            uint l; __builtin_memcpy(&l, &l2, 4);
            hu[j] = h; lu[j] = l;
        }
        *reinterpret_cast<uint4*>(&Al[buf][smi][0][sflane][0]) = make_uint4(hu[0], hu[1], hu[2], hu[3]);
        *reinterpret_cast<uint4*>(&Al[buf][smi][1][sflane][0]) = make_uint4(lu[0], lu[1], lu[2], lu[3]);
    };
    auto compute = [&](int buf, bf16x8 b0, bf16x8 b1) {
#pragma unroll
        for (int mi = 0; mi < 4; mi++) {
            bf16x8 ah = *reinterpret_cast<const bf16x8*>(&Al[buf][mi][0][lane][0]);
            bf16x8 al = *reinterpret_cast<const bf16x8*>(&Al[buf][mi][1][lane][0]);
            acc[mi][0] = __builtin_amdgcn_mfma_f32_16x16x32_bf16(ah, b0, acc[mi][0], 0, 0, 0);
            acc[mi][0] = __builtin_amdgcn_mfma_f32_16x16x32_bf16(al, b0, acc[mi][0], 0, 0, 0);
            acc[mi][1] = __builtin_amdgcn_mfma_f32_16x16x32_bf16(ah, b1, acc[mi][1], 0, 0, 0);
            acc[mi][1] = __builtin_amdgcn_mfma_f32_16x16x32_bf16(al, b1, acc[mi][1], 0, 0, 0);
        }
    };

    loadA(0);
    bcur0 = *reinterpret_cast<const bf16x8*>(Wt_hi + bgoff0);
    bcur1 = *reinterpret_cast<const bf16x8*>(Wt_hi + bgoff1);
    stageA(0);
    __syncthreads();

    for (int kt = 0; kt < 16; kt++) {
        const int cb = kt & 1;
        if (kt < 15) {
            loadA((kt + 1) * 32);
            bnxt0 = *reinterpret_cast<const bf16x8*>(Wt_hi + bgoff0 + (kt + 1) * 32);
            bnxt1 = *reinterpret_cast<const bf16x8*>(Wt_hi + bgoff1 + (kt + 1) * 32);
        }
        compute(cb, bcur0, bcur1);
        if (kt < 15) {
            stageA(cb ^ 1);
            bcur0 = bnxt0; bcur1 = bnxt1;
            __syncthreads();
        }
    }

    // epilogue: C layout col=lane&15, row=4*(lane>>4)+reg; store bf16
#pragma unroll
    for (int mi = 0; mi < 4; mi++) {
        int rbase = bm + mi * 16 + lq * 4;
#pragma unroll
        for (int r = 0; r < 4; r++) {
            int row = rbase + r;
            if (row < n) {
                float ns = norm_src[row];
#pragma unroll
                for (int ni = 0; ni < 2; ni++) {
                    h1g[(size_t)row * F1 + w * 32 + ni * 16 + l15] = f2bf(acc[mi][ni][r] * ns);
                }
            }
        }
    }
}

// ---------------- Agg1: h1(bf16) = relu(segsum(h1g[src]) * norm_dst + b1), one wave per node ----------------
__global__ __launch_bounds__(256)
void agg1_kernel(const ushort* __restrict__ h1g, const int* __restrict__ row_off,
                 const int* __restrict__ edge_src, const float* __restrict__ norm_dst,
                 const float* __restrict__ b1, ushort* __restrict__ h1, int n) {
    int wid = (blockIdx.x * blockDim.x + threadIdx.x) >> 6;
    int lane = threadIdx.x & 63;
    if (wid >= n) return;
    int beg = row_off[wid], end = row_off[wid + 1];
    float a0 = 0.f, a1 = 0.f;
    int e = beg;
    for (; e + 3 < end; e += 4) {
        int s0 = edge_src[e + 0];
        int s1 = edge_src[e + 1];
        int s2 = edge_src[e + 2];
        int s3 = edge_src[e + 3];
        uint v0 = *reinterpret_cast<const uint*>(&h1g[(size_t)s0 * F1 + lane * 2]);
        uint v1 = *reinterpret_cast<const uint*>(&h1g[(size_t)s1 * F1 + lane * 2]);
        uint v2 = *reinterpret_cast<const uint*>(&h1g[(size_t)s2 * F1 + lane * 2]);
        uint v3 = *reinterpret_cast<const uint*>(&h1g[(size_t)s3 * F1 + lane * 2]);
        a0 += (__uint_as_float(v0 << 16) + __uint_as_float(v1 << 16)) +
              (__uint_as_float(v2 << 16) + __uint_as_float(v3 << 16));
        a1 += (__uint_as_float(v0 & 0xffff0000u) + __uint_as_float(v1 & 0xffff0000u)) +
              (__uint_as_float(v2 & 0xffff0000u) + __uint_as_float(v3 & 0xffff0000u));
    }
    for (; e < end; ++e) {
        int s = edge_src[e];
        uint v = *reinterpret_cast<const uint*>(&h1g[(size_t)s * F1 + lane * 2]);
        a0 += __uint_as_float(v << 16);
        a1 += __uint_as_float(v & 0xffff0000u);
    }
    float nd = norm_dst[wid];
    float o0 = fmaxf(a0 * nd + b1[lane * 2 + 0], 0.f);
    float o1 = fmaxf(a1 * nd + b1[lane * 2 + 1], 0.f);
    __hip_bfloat162 p2 = __float22bfloat162_rn(make_float2(o0, o1));
    uint pu; __builtin_memcpy(&pu, &p2, 4);
    *reinterpret_cast<uint*>(&h1[(size_t)wid * F1 + lane * 2]) = pu;
}

// ---------------- GEMM2: h2g(bf16) = (h1 @ W2) * norm_src  [n x 128] @ [128 x 40] ----------------
__global__ __launch_bounds__(256)
void gemm2_kernel(const ushort* __restrict__ h1, const float* __restrict__ W2,
                  const float* __restrict__ norm_src, ushort* __restrict__ h2g, int n) {
    __shared__ __align__(16) float W2s[F1][F2];
    for (int i = threadIdx.x; i < F1 * F2; i += 256)
        W2s[i / F2][i % F2] = W2[i];
    __syncthreads();
    int node = blockIdx.x * 256 + threadIdx.x;
    if (node >= n) return;
    float nrm = norm_src[node];
    f32x4 acc4[10] = {};
    const ushort* row = &h1[(size_t)node * F1];
    for (int kc = 0; kc < 16; kc++) {
        uint4 u = *reinterpret_cast<const uint4*>(&row[kc * 8]);
        uint uu[4] = {u.x, u.y, u.z, u.w};
        float f[8];
#pragma unroll
        for (int i = 0; i < 4; i++) {
            f[2 * i + 0] = __uint_as_float(uu[i] << 16);
            f[2 * i + 1] = __uint_as_float(uu[i] & 0xffff0000u);
        }
#pragma unroll
        for (int j = 0; j < 8; j++) {
#pragma unroll
            for (int c4 = 0; c4 < 10; c4++) {
                f32x4 wv = *reinterpret_cast<const f32x4*>(&W2s[kc * 8 + j][c4 * 4]);
                acc4[c4] += f[j] * wv;
            }
        }
    }
    ushort* orow = &h2g[(size_t)node * F2];
#pragma unroll
    for (int c4 = 0; c4 < 10; c4++) {
        f32x4 o = acc4[c4] * nrm;
        __hip_bfloat162 pa = __float22bfloat162_rn(make_float2(o[0], o[1]));
        __hip_bfloat162 pb = __float22bfloat162_rn(make_float2(o[2], o[3]));
        uint2 pk;
        __builtin_memcpy(&pk.x, &pa, 4);
        __builtin_memcpy(&pk.y, &pb, 4);
        *reinterpret_cast<uint2*>(&orow[c4 * 4]) = pk;
    }
}

// ---------------- Agg2: out = segsum(h2g[src]) * norm_dst + b2, one wave per node ----------------
__global__ __launch_bounds__(256)
void agg2_kernel(const ushort* __restrict__ h2g, const int* __restrict__ row_off,
                 const int* __restrict__ edge_src, const float* __restrict__ norm_dst,
                 const float* __restrict__ b2, float* __restrict__ out, int n) {
    int wid = (blockIdx.x * blockDim.x + threadIdx.x) >> 6;
    int lane = threadIdx.x & 63;
    if (wid >= n) return;
    int beg = row_off[wid], end = row_off[wid + 1];
    float a0 = 0.f, a1 = 0.f, b0 = 0.f, b1v = 0.f;
    int e = beg;
    const bool act = lane < 20;
    for (; e + 3 < end; e += 4) {
        int s0 = edge_src[e + 0];
        int s1 = edge_src[e + 1];
        int s2 = edge_src[e + 2];
        int s3 = edge_src[e + 3];
        if (act) {
            uint v0 = *reinterpret_cast<const uint*>(&h2g[(size_t)s0 * F2 + lane * 2]);
            uint v1 = *reinterpret_cast<const uint*>(&h2g[(size_t)s1 * F2 + lane * 2]);
            uint v2 = *reinterpret_cast<const uint*>(&h2g[(size_t)s2 * F2 + lane * 2]);
            uint v3 = *reinterpret_cast<const uint*>(&h2g[(size_t)s3 * F2 + lane * 2]);
            a0 += (__uint_as_float(v0 << 16) + __uint_as_float(v1 << 16)) +
                  (__uint_as_float(v2 << 16) + __uint_as_float(v3 << 16));
            b0 += (__uint_as_float(v0 & 0xffff0000u) + __uint_as_float(v1 & 0xffff0000u)) +
                  (__uint_as_float(v2 & 0xffff0000u) + __uint_as_float(v3 & 0xffff0000u));
        }
    }
    for (; e < end; ++e) {
        int s = edge_src[e];
        if (act) {
            uint v = *reinterpret_cast<const uint*>(&h2g[(size_t)s * F2 + lane * 2]);
            a1 += __uint_as_float(v << 16);
            b1v += __uint_as_float(v & 0xffff0000u);
        }
    }
    if (act) {
        float nd = norm_dst[wid];
        float o0 = (a0 + a1) * nd + b2[lane * 2 + 0];
        float o1 = (b0 + b1v) * nd + b2[lane * 2 + 1];
        *reinterpret_cast<float2*>(&out[(size_t)wid * F2 + lane * 2]) = make_float2(o0, o1);
    }
}

extern "C" void kernel_launch(void* const* d_in, const int* in_sizes, int n_in,
                              void* d_out, int out_size, void* d_ws, size_t ws_size,
                              hipStream_t stream) {
    const float* x  = (const float*)d_in[0];
    const float* W1 = (const float*)d_in[1];
    const float* b1 = (const float*)d_in[2];
    const float* W2 = (const float*)d_in[3];
    const float* b2 = (const float*)d_in[4];
    const int* src  = (const int*)d_in[5];
    const int* dst  = (const int*)d_in[6];
    float* out = (float*)d_out;

    const int n = in_sizes[0] / F0;
    const int E = in_sizes[5];
    const int nb = (n + 255) / 256;
    const int P = (n + NRP - 1) / NRP;

    char* ws = (char*)d_ws;
    auto alloc = [&](size_t bytes) -> char* {
        char* p = ws;
        ws += (bytes + 255) & ~(size_t)255;
        return p;
    };
    int* row_off   = (int*)alloc((size_t)(n + 1) * 4);
    int* bsum      = (int*)alloc(256 * 4);
    int* edge_srcs = (int*)alloc((size_t)E * 4);
    float* norm_src_d = (float*)alloc((size_t)n * 4);
    float* norm_dst_d = (float*)alloc((size_t)n * 4);
    ushort* W1t_hi = (ushort*)alloc((size_t)F1 * F0 * 2);
    ushort* h1g = (ushort*)alloc((size_t)n * F1 * 2);   // bf16
    ushort* h1  = (ushort*)alloc((size_t)n * F1 * 2);   // bf16
    ushort* h2g = h1g;   // reuse after agg1: n*F2*2 (4MB) <= n*F1*2 (12.8MB)

    // per-slice count/offset arrays alias h1g (not yet live): 2 * G_SL * n * 4 = n*F1*2 bytes
    int* Gsrc = (int*)h1g;
    int* Gdst = Gsrc + (size_t)G_SL * n;

    hist_kernel<<<P * G_SL, 256, 0, stream>>>(src, dst, Gsrc, Gdst, n, E);
    scanA_kernel<<<nb, 256, 0, stream>>>(Gsrc, Gdst, norm_src_d, norm_dst_d, row_off, bsum, n);
    finalize_kernel<<<nb, 256, 0, stream>>>(row_off, bsum, Gdst, n);
    place_kernel<<<P * G_SL, 256, 0, stream>>>(src, dst, Gdst, edge_srcs, n, E);
    wconv1_kernel<<<(F0 * F1) / 256, 256, 0, stream>>>(W1, W1t_hi);
    gemm1_mfma<<<(n + BM - 1) / BM, 256, 0, stream>>>(x, W1t_hi, norm_src_d, h1g, n);
    agg1_kernel<<<(n + 3) / 4, 256, 0, stream>>>(h1g, row_off, edge_srcs, norm_dst_d, b1, h1, n);
    gemm2_kernel<<<(n + 255) / 256, 256, 0, stream>>>(h1, W2, norm_src_d, h2g, n);
    agg2_kernel<<<(n + 3) / 4, 256, 0, stream>>>(h2g, row_off, edge_srcs, norm_dst_d, b2, out, n);
}

// Round 6
// 195.030 us; speedup vs baseline: 2.5845x; 1.3105x over previous
//
#include <hip/hip_runtime.h>
#include <hip/hip_bf16.h>

#define F0 512
#define F1 128
#define F2 40

#define NRP 12800   // nodes per histogram partition
#define G_SL 64     // edge slices

typedef __attribute__((ext_vector_type(8))) short bf16x8;
typedef __attribute__((ext_vector_type(4))) float f32x4;

__device__ inline ushort f2bf(float f) {
    union { float f; uint u; } v; v.f = f;
    uint u = v.u;
    uint r = u + 0x7fffu + ((u >> 16) & 1u);   // RNE
    return (ushort)(r >> 16);
}
__device__ inline float bf2f(ushort h) {
    union { uint u; float f; } v; v.u = ((uint)h) << 16;
    return v.f;
}

// ---------------- pass 1: per-slice histograms (packed ushort LDS counters, no global atomics) ----------------
// grid = P * G_SL = 256 blocks of 1024 threads: all CUs busy, 16 waves/CU for latency hiding.
__global__ __launch_bounds__(1024)
void hist_kernel(const int* __restrict__ src, const int* __restrict__ dst,
                 ushort* __restrict__ Gsrc, ushort* __restrict__ Gdst, int n, int E) {
    __shared__ uint cs[NRP / 2];
    __shared__ uint cd[NRP / 2];
    const int p = blockIdx.x / G_SL;
    const int g = blockIdx.x % G_SL;
    const int base = p * NRP;
    for (int i = threadIdx.x; i < NRP / 2; i += 1024) { cs[i] = 0; cd[i] = 0; }
    __syncthreads();
    const int Epg = (E + G_SL - 1) / G_SL;
    const int e0 = g * Epg;
    const int e1 = min(E, e0 + Epg);
    for (int i = e0 + (int)threadIdx.x; i < e1; i += 1024) {
        int s = src[i], d = dst[i];
        unsigned so = (unsigned)(s - base);
        unsigned dd = (unsigned)(d - base);
        if (so < (unsigned)NRP) atomicAdd(&cs[so >> 1], 1u << ((so & 1) * 16));
        if (dd < (unsigned)NRP) atomicAdd(&cd[dd >> 1], 1u << ((dd & 1) * 16));
    }
    __syncthreads();
    const int lim = min(NRP, n - base);
    for (int i = threadIdx.x; i < lim; i += 1024) {
        uint pcs = cs[i >> 1], pcd = cd[i >> 1];
        int sh = (i & 1) * 16;
        Gsrc[(size_t)g * n + base + i] = (ushort)((pcs >> sh) & 0xffffu);
        Gdst[(size_t)g * n + base + i] = (ushort)((pcd >> sh) & 0xffffu);
    }
}

// ---------------- pass 2: degree sums + norms + per-256-block inclusive scan ----------------
__global__ __launch_bounds__(256)
void scanA_kernel(const ushort* __restrict__ Gsrc, const ushort* __restrict__ Gdst,
                  float* __restrict__ norm_src, float* __restrict__ norm_dst,
                  int* __restrict__ row_off, int* __restrict__ bsum, int n) {
    __shared__ int sm[256];
    int i = blockIdx.x * 256 + threadIdx.x;
    int s = 0, d = 0;
    if (i < n) {
#pragma unroll
        for (int g = 0; g < G_SL; g++) {
            s += Gsrc[(size_t)g * n + i];
            d += Gdst[(size_t)g * n + i];
        }
        norm_src[i] = s > 0 ? rsqrtf((float)s) : 0.f;
        norm_dst[i] = d > 0 ? rsqrtf((float)d) : 0.f;
    }
    sm[threadIdx.x] = (i < n) ? d : 0;
    __syncthreads();
    for (int off = 1; off < 256; off <<= 1) {
        int t = (threadIdx.x >= (unsigned)off) ? sm[threadIdx.x - off] : 0;
        __syncthreads();
        sm[threadIdx.x] += t;
        __syncthreads();
    }
    if (i < n) row_off[i + 1] = sm[threadIdx.x];   // raw: in-block inclusive
    if (threadIdx.x == 255) bsum[blockIdx.x] = sm[255];
}

// ---------------- pass 3: finalize row_off (global exclusive) + per-slice start offsets ----------------
__global__ __launch_bounds__(256)
void finalize_kernel(int* __restrict__ row_off, const int* __restrict__ bsum,
                     const ushort* __restrict__ Gdst, int* __restrict__ Goff, int n) {
    __shared__ int sm[256];
    const int b = blockIdx.x;
    const int t = threadIdx.x;
    sm[t] = (t < b) ? bsum[t] : 0;
    __syncthreads();
#pragma unroll
    for (int off = 128; off > 0; off >>= 1) {
        if (t < off) sm[t] += sm[t + off];
        __syncthreads();
    }
    const int excl = sm[0];
    const int v = b * 256 + t;
    if (v >= n) return;
    int raw = row_off[v];                       // each index touched only by its own thread
    int start = excl + ((t == 0) ? 0 : raw);
    if (v == n - 1) {
        int rawn = row_off[n];
        row_off[n] = excl + rawn;
    }
    row_off[v] = start;
    int run = start;
#pragma unroll
    for (int g = 0; g < G_SL; g++) {
        size_t idx = (size_t)g * n + v;
        Goff[idx] = run;
        run += Gdst[idx];
    }
}

// ---------------- edge placement (counting sort; int LDS cursors seeded with global offsets) ----------------
__global__ __launch_bounds__(1024)
void place_kernel(const int* __restrict__ src, const int* __restrict__ dst,
                  const int* __restrict__ Goff, int* __restrict__ edge_src, int n, int E) {
    __shared__ int cur[NRP];   // 51.2KB
    const int p = blockIdx.x / G_SL;
    const int g = blockIdx.x % G_SL;
    const int base = p * NRP;
    const int lim = min(NRP, n - base);
    for (int i = threadIdx.x; i < lim; i += 1024)
        cur[i] = Goff[(size_t)g * n + base + i];
    __syncthreads();
    const int Epg = (E + G_SL - 1) / G_SL;
    const int e0 = g * Epg;
    const int e1 = min(E, e0 + Epg);
    for (int i = e0 + (int)threadIdx.x; i < e1; i += 1024) {
        int d = dst[i];
        unsigned dd = (unsigned)(d - base);
        if (dd < (unsigned)lim) {
            int pos = atomicAdd(&cur[dd], 1);
            edge_src[pos] = src[i];
        }
    }
}

// ---------------- W1 preconvert: [512][128] f32 -> bf16 transposed [128][512] ----------------
__global__ __launch_bounds__(256)
void wconv1_kernel(const float* __restrict__ W1, ushort* __restrict__ Wt_hi) {
    int idx = blockIdx.x * 256 + threadIdx.x;  // 0..65535
    int k = idx >> 7, nn = idx & 127;
    Wt_hi[nn * F0 + k] = f2bf(W1[idx]);
}

// ---------------- GEMM1 (MFMA, split-A bf16): h1g(bf16) = (x @ W1) * norm_src ----------------
// BM=64, BK=32. Wave w owns cols [w*32, w*32+32) x all 64 rows. A staged in LDS in
// fragment-linear layout (ds_write/ds_read both lane-consecutive 16B = conflict-free).
// B (bf16 W1t, 128KB, L2-hot) loaded per-lane direct from global, prefetched 1 k-tile ahead.
#define BM 64
__global__ __launch_bounds__(256)
void gemm1_mfma(const float* __restrict__ x, const ushort* __restrict__ Wt_hi,
                const float* __restrict__ norm_src, ushort* __restrict__ h1g, int n) {
    __shared__ __align__(16) ushort Al[2][4][2][64][8];   // [buf][mi][hi/lo][flane][8] = 16KB

    const int tid = threadIdx.x;
    const int lane = tid & 63;
    const int w = tid >> 6;
    const int l15 = lane & 15;
    const int lq = lane >> 4;
    const int bm = blockIdx.x * BM;

    const int smi = tid >> 6;
    const int sflane = tid & 63;
    const int srow = smi * 16 + (tid & 15);
    const int skc = (tid >> 4) & 3;
    const int grow = bm + srow;
    const bool arok = grow < n;
    const float* xrow = x + (size_t)(arok ? grow : 0) * F0 + skc * 8;

    const size_t bgoff0 = (size_t)((w * 2 + 0) * 16 + l15) * F0 + lq * 8;
    const size_t bgoff1 = (size_t)((w * 2 + 1) * 16 + l15) * F0 + lq * 8;

    f32x4 acc[4][2] = {};
    float4 a0, a1;
    bf16x8 bcur0, bcur1, bnxt0, bnxt1;

    auto loadA = [&](int k0) {
        if (arok) {
            a0 = *reinterpret_cast<const float4*>(xrow + k0);
            a1 = *reinterpret_cast<const float4*>(xrow + k0 + 4);
        } else {
            a0 = make_float4(0.f, 0.f, 0.f, 0.f);
            a1 = a0;
        }
    };
    auto stageA = [&](int buf) {
        float cf[8] = {a0.x, a0.y, a0.z, a0.w, a1.x, a1.y, a1.z, a1.w};
        uint hu[4], lu[4];
#pragma unroll
        for (int j = 0; j < 4; j++) {
            float fa = cf[2 * j], fb = cf[2 * j + 1];
            __hip_bfloat162 h2 = __float22bfloat162_rn(make_float2(fa, fb));
            uint h; __builtin_memcpy(&h, &h2, 4);
            float ra = __uint_as_float(h << 16);
            float rb = __uint_as_float(h & 0xffff0000u);
            __hip_bfloat162 l2 = __float22bfloat162_rn(make_float2(fa - ra, fb - rb));
            uint l; __builtin_memcpy(&l, &l2, 4);
            hu[j] = h; lu[j] = l;
        }
        *reinterpret_cast<uint4*>(&Al[buf][smi][0][sflane][0]) = make_uint4(hu[0], hu[1], hu[2], hu[3]);
        *reinterpret_cast<uint4*>(&Al[buf][smi][1][sflane][0]) = make_uint4(lu[0], lu[1], lu[2], lu[3]);
    };
    auto compute = [&](int buf, bf16x8 b0, bf16x8 b1) {
#pragma unroll
        for (int mi = 0; mi < 4; mi++) {
            bf16x8 ah = *reinterpret_cast<const bf16x8*>(&Al[buf][mi][0][lane][0]);
            bf16x8 al = *reinterpret_cast<const bf16x8*>(&Al[buf][mi][1][lane][0]);
            acc[mi][0] = __builtin_amdgcn_mfma_f32_16x16x32_bf16(ah, b0, acc[mi][0], 0, 0, 0);
            acc[mi][0] = __builtin_amdgcn_mfma_f32_16x16x32_bf16(al, b0, acc[mi][0], 0, 0, 0);
            acc[mi][1] = __builtin_amdgcn_mfma_f32_16x16x32_bf16(ah, b1, acc[mi][1], 0, 0, 0);
            acc[mi][1] = __builtin_amdgcn_mfma_f32_16x16x32_bf16(al, b1, acc[mi][1], 0, 0, 0);
        }
    };

    loadA(0);
    bcur0 = *reinterpret_cast<const bf16x8*>(Wt_hi + bgoff0);
    bcur1 = *reinterpret_cast<const bf16x8*>(Wt_hi + bgoff1);
    stageA(0);
    __syncthreads();

    for (int kt = 0; kt < 16; kt++) {
        const int cb = kt & 1;
        if (kt < 15) {
            loadA((kt + 1) * 32);
            bnxt0 = *reinterpret_cast<const bf16x8*>(Wt_hi + bgoff0 + (kt + 1) * 32);
            bnxt1 = *reinterpret_cast<const bf16x8*>(Wt_hi + bgoff1 + (kt + 1) * 32);
        }
        compute(cb, bcur0, bcur1);
        if (kt < 15) {
            stageA(cb ^ 1);
            bcur0 = bnxt0; bcur1 = bnxt1;
            __syncthreads();
        }
    }

    // epilogue: C layout col=lane&15, row=4*(lane>>4)+reg; store bf16
#pragma unroll
    for (int mi = 0; mi < 4; mi++) {
        int rbase = bm + mi * 16 + lq * 4;
#pragma unroll
        for (int r = 0; r < 4; r++) {
            int row = rbase + r;
            if (row < n) {
                float ns = norm_src[row];
#pragma unroll
                for (int ni = 0; ni < 2; ni++) {
                    h1g[(size_t)row * F1 + w * 32 + ni * 16 + l15] = f2bf(acc[mi][ni][r] * ns);
                }
            }
        }
    }
}

// ---------------- Agg1: h1(bf16) = relu(segsum(h1g[src]) * norm_dst + b1), one wave per node ----------------
__global__ __launch_bounds__(256)
void agg1_kernel(const ushort* __restrict__ h1g, const int* __restrict__ row_off,
                 const int* __restrict__ edge_src, const float* __restrict__ norm_dst,
                 const float* __restrict__ b1, ushort* __restrict__ h1, int n) {
    int wid = (blockIdx.x * blockDim.x + threadIdx.x) >> 6;
    int lane = threadIdx.x & 63;
    if (wid >= n) return;
    int beg = row_off[wid], end = row_off[wid + 1];
    float a0 = 0.f, a1 = 0.f;
    int e = beg;
    for (; e + 3 < end; e += 4) {
        int s0 = edge_src[e + 0];
        int s1 = edge_src[e + 1];
        int s2 = edge_src[e + 2];
        int s3 = edge_src[e + 3];
        uint v0 = *reinterpret_cast<const uint*>(&h1g[(size_t)s0 * F1 + lane * 2]);
        uint v1 = *reinterpret_cast<const uint*>(&h1g[(size_t)s1 * F1 + lane * 2]);
        uint v2 = *reinterpret_cast<const uint*>(&h1g[(size_t)s2 * F1 + lane * 2]);
        uint v3 = *reinterpret_cast<const uint*>(&h1g[(size_t)s3 * F1 + lane * 2]);
        a0 += (__uint_as_float(v0 << 16) + __uint_as_float(v1 << 16)) +
              (__uint_as_float(v2 << 16) + __uint_as_float(v3 << 16));
        a1 += (__uint_as_float(v0 & 0xffff0000u) + __uint_as_float(v1 & 0xffff0000u)) +
              (__uint_as_float(v2 & 0xffff0000u) + __uint_as_float(v3 & 0xffff0000u));
    }
    for (; e < end; ++e) {
        int s = edge_src[e];
        uint v = *reinterpret_cast<const uint*>(&h1g[(size_t)s * F1 + lane * 2]);
        a0 += __uint_as_float(v << 16);
        a1 += __uint_as_float(v & 0xffff0000u);
    }
    float nd = norm_dst[wid];
    float o0 = fmaxf(a0 * nd + b1[lane * 2 + 0], 0.f);
    float o1 = fmaxf(a1 * nd + b1[lane * 2 + 1], 0.f);
    __hip_bfloat162 p2 = __float22bfloat162_rn(make_float2(o0, o1));
    uint pu; __builtin_memcpy(&pu, &p2, 4);
    *reinterpret_cast<uint*>(&h1[(size_t)wid * F1 + lane * 2]) = pu;
}

// ---------------- GEMM2: h2g(bf16) = (h1 @ W2) * norm_src  [n x 128] @ [128 x 40] ----------------
__global__ __launch_bounds__(256)
void gemm2_kernel(const ushort* __restrict__ h1, const float* __restrict__ W2,
                  const float* __restrict__ norm_src, ushort* __restrict__ h2g, int n) {
    __shared__ __align__(16) float W2s[F1][F2];
    for (int i = threadIdx.x; i < F1 * F2; i += 256)
        W2s[i / F2][i % F2] = W2[i];
    __syncthreads();
    int node = blockIdx.x * 256 + threadIdx.x;
    if (node >= n) return;
    float nrm = norm_src[node];
    f32x4 acc4[10] = {};
    const ushort* row = &h1[(size_t)node * F1];
    for (int kc = 0; kc < 16; kc++) {
        uint4 u = *reinterpret_cast<const uint4*>(&row[kc * 8]);
        uint uu[4] = {u.x, u.y, u.z, u.w};
        float f[8];
#pragma unroll
        for (int i = 0; i < 4; i++) {
            f[2 * i + 0] = __uint_as_float(uu[i] << 16);
            f[2 * i + 1] = __uint_as_float(uu[i] & 0xffff0000u);
        }
#pragma unroll
        for (int j = 0; j < 8; j++) {
#pragma unroll
            for (int c4 = 0; c4 < 10; c4++) {
                f32x4 wv = *reinterpret_cast<const f32x4*>(&W2s[kc * 8 + j][c4 * 4]);
                acc4[c4] += f[j] * wv;
            }
        }
    }
    ushort* orow = &h2g[(size_t)node * F2];
#pragma unroll
    for (int c4 = 0; c4 < 10; c4++) {
        f32x4 o = acc4[c4] * nrm;
        __hip_bfloat162 pa = __float22bfloat162_rn(make_float2(o[0], o[1]));
        __hip_bfloat162 pb = __float22bfloat162_rn(make_float2(o[2], o[3]));
        uint2 pk;
        __builtin_memcpy(&pk.x, &pa, 4);
        __builtin_memcpy(&pk.y, &pb, 4);
        *reinterpret_cast<uint2*>(&orow[c4 * 4]) = pk;
    }
}

// ---------------- Agg2: out = segsum(h2g[src]) * norm_dst + b2, one wave per node ----------------
__global__ __launch_bounds__(256)
void agg2_kernel(const ushort* __restrict__ h2g, const int* __restrict__ row_off,
                 const int* __restrict__ edge_src, const float* __restrict__ norm_dst,
                 const float* __restrict__ b2, float* __restrict__ out, int n) {
    int wid = (blockIdx.x * blockDim.x + threadIdx.x) >> 6;
    int lane = threadIdx.x & 63;
    if (wid >= n) return;
    int beg = row_off[wid], end = row_off[wid + 1];
    float a0 = 0.f, a1 = 0.f, b0 = 0.f, b1v = 0.f;
    int e = beg;
    const bool act = lane < 20;
    for (; e + 3 < end; e += 4) {
        int s0 = edge_src[e + 0];
        int s1 = edge_src[e + 1];
        int s2 = edge_src[e + 2];
        int s3 = edge_src[e + 3];
        if (act) {
            uint v0 = *reinterpret_cast<const uint*>(&h2g[(size_t)s0 * F2 + lane * 2]);
            uint v1 = *reinterpret_cast<const uint*>(&h2g[(size_t)s1 * F2 + lane * 2]);
            uint v2 = *reinterpret_cast<const uint*>(&h2g[(size_t)s2 * F2 + lane * 2]);
            uint v3 = *reinterpret_cast<const uint*>(&h2g[(size_t)s3 * F2 + lane * 2]);
            a0 += (__uint_as_float(v0 << 16) + __uint_as_float(v1 << 16)) +
                  (__uint_as_float(v2 << 16) + __uint_as_float(v3 << 16));
            b0 += (__uint_as_float(v0 & 0xffff0000u) + __uint_as_float(v1 & 0xffff0000u)) +
                  (__uint_as_float(v2 & 0xffff0000u) + __uint_as_float(v3 & 0xffff0000u));
        }
    }
    for (; e < end; ++e) {
        int s = edge_src[e];
        if (act) {
            uint v = *reinterpret_cast<const uint*>(&h2g[(size_t)s * F2 + lane * 2]);
            a1 += __uint_as_float(v << 16);
            b1v += __uint_as_float(v & 0xffff0000u);
        }
    }
    if (act) {
        float nd = norm_dst[wid];
        float o0 = (a0 + a1) * nd + b2[lane * 2 + 0];
        float o1 = (b0 + b1v) * nd + b2[lane * 2 + 1];
        *reinterpret_cast<float2*>(&out[(size_t)wid * F2 + lane * 2]) = make_float2(o0, o1);
    }
}

extern "C" void kernel_launch(void* const* d_in, const int* in_sizes, int n_in,
                              void* d_out, int out_size, void* d_ws, size_t ws_size,
                              hipStream_t stream) {
    const float* x  = (const float*)d_in[0];
    const float* W1 = (const float*)d_in[1];
    const float* b1 = (const float*)d_in[2];
    const float* W2 = (const float*)d_in[3];
    const float* b2 = (const float*)d_in[4];
    const int* src  = (const int*)d_in[5];
    const int* dst  = (const int*)d_in[6];
    float* out = (float*)d_out;

    const int n = in_sizes[0] / F0;
    const int E = in_sizes[5];
    const int nb = (n + 255) / 256;
    const int P = (n + NRP - 1) / NRP;

    char* ws = (char*)d_ws;
    auto alloc = [&](size_t bytes) -> char* {
        char* p = ws;
        ws += (bytes + 255) & ~(size_t)255;
        return p;
    };
    int* row_off   = (int*)alloc((size_t)(n + 1) * 4);
    int* bsum      = (int*)alloc(256 * 4);
    int* edge_srcs = (int*)alloc((size_t)E * 4);
    float* norm_src_d = (float*)alloc((size_t)n * 4);
    float* norm_dst_d = (float*)alloc((size_t)n * 4);
    ushort* W1t_hi = (ushort*)alloc((size_t)F1 * F0 * 2);
    ushort* h1g = (ushort*)alloc((size_t)n * F1 * 2);   // bf16 (12.8MB)
    ushort* h1  = (ushort*)alloc((size_t)n * F1 * 2);   // bf16 (12.8MB)
    ushort* h2g = h1g;   // reuse after agg1: n*F2*2 <= n*F1*2

    // aliasing (all dead before their hosts go live):
    //   Gsrc/Gdst (ushort counts, 2 * G_SL*n*2 = 12.8MB) -> h1g region (live from gemm1)
    //   Goff      (int offsets,       G_SL*n*4 = 12.8MB) -> h1  region (live from agg1)
    ushort* Gsrc = (ushort*)h1g;
    ushort* Gdst = Gsrc + (size_t)G_SL * n;
    int* Goff = (int*)h1;

    hist_kernel<<<P * G_SL, 1024, 0, stream>>>(src, dst, Gsrc, Gdst, n, E);
    scanA_kernel<<<nb, 256, 0, stream>>>(Gsrc, Gdst, norm_src_d, norm_dst_d, row_off, bsum, n);
    finalize_kernel<<<nb, 256, 0, stream>>>(row_off, bsum, Gdst, Goff, n);
    place_kernel<<<P * G_SL, 1024, 0, stream>>>(src, dst, Goff, edge_srcs, n, E);
    wconv1_kernel<<<(F0 * F1) / 256, 256, 0, stream>>>(W1, W1t_hi);
    gemm1_mfma<<<(n + BM - 1) / BM, 256, 0, stream>>>(x, W1t_hi, norm_src_d, h1g, n);
    agg1_kernel<<<(n + 3) / 4, 256, 0, stream>>>(h1g, row_off, edge_srcs, norm_dst_d, b1, h1, n);
    gemm2_kernel<<<(n + 255) / 256, 256, 0, stream>>>(h1, W2, norm_src_d, h2g, n);
    agg2_kernel<<<(n + 3) / 4, 256, 0, stream>>>(h2g, row_off, edge_srcs, norm_dst_d, b2, out, n);
}

// Round 7
// 192.458 us; speedup vs baseline: 2.6190x; 1.0134x over previous
//
#include <hip/hip_runtime.h>
#include <hip/hip_bf16.h>

#define F0 512
#define F1 128
#define F2 40

#define NRP 12800   // nodes per histogram partition
#define G_SL 64     // edge slices

typedef __attribute__((ext_vector_type(8))) short bf16x8;
typedef __attribute__((ext_vector_type(4))) float f32x4;

__device__ inline ushort f2bf(float f) {
    union { float f; uint u; } v; v.f = f;
    uint u = v.u;
    uint r = u + 0x7fffu + ((u >> 16) & 1u);   // RNE
    return (ushort)(r >> 16);
}

// ---------------- pass 1: per-slice histograms + fused W1 preconvert ----------------
// grid = P * G_SL = 256 blocks of 1024 threads.
__global__ __launch_bounds__(1024)
void hist_kernel(const int* __restrict__ src, const int* __restrict__ dst,
                 ushort* __restrict__ Gsrc, ushort* __restrict__ Gdst,
                 const float* __restrict__ W1, ushort* __restrict__ Wt, int n, int E) {
    // fused W1 -> bf16 transpose: first 64 blocks cover 64*1024 = 65536 = F0*F1 elems
    if (blockIdx.x < (F0 * F1) / 1024) {
        int idx = blockIdx.x * 1024 + threadIdx.x;
        int k = idx >> 7, nn = idx & 127;
        Wt[nn * F0 + k] = f2bf(W1[idx]);
    }
    __shared__ uint cs[NRP / 2];
    __shared__ uint cd[NRP / 2];
    const int p = blockIdx.x / G_SL;
    const int g = blockIdx.x % G_SL;
    const int base = p * NRP;
    for (int i = threadIdx.x; i < NRP / 2; i += 1024) { cs[i] = 0; cd[i] = 0; }
    __syncthreads();
    const int Epg = (E + G_SL - 1) / G_SL;
    const int e0 = g * Epg;
    const int e1 = min(E, e0 + Epg);
    for (int i = e0 + (int)threadIdx.x; i < e1; i += 1024) {
        int s = src[i], d = dst[i];
        unsigned so = (unsigned)(s - base);
        unsigned dd = (unsigned)(d - base);
        if (so < (unsigned)NRP) atomicAdd(&cs[so >> 1], 1u << ((so & 1) * 16));
        if (dd < (unsigned)NRP) atomicAdd(&cd[dd >> 1], 1u << ((dd & 1) * 16));
    }
    __syncthreads();
    const int lim = min(NRP, n - base);
    for (int i = threadIdx.x; i < lim; i += 1024) {
        uint pcs = cs[i >> 1], pcd = cd[i >> 1];
        int sh = (i & 1) * 16;
        Gsrc[(size_t)g * n + base + i] = (ushort)((pcs >> sh) & 0xffffu);
        Gdst[(size_t)g * n + base + i] = (ushort)((pcd >> sh) & 0xffffu);
    }
}

// ---------------- pass 2: degree sums + norms + per-256-block inclusive scan ----------------
__global__ __launch_bounds__(256)
void scanA_kernel(const ushort* __restrict__ Gsrc, const ushort* __restrict__ Gdst,
                  float* __restrict__ norm_src, float* __restrict__ norm_dst,
                  int* __restrict__ row_off, int* __restrict__ bsum, int n) {
    __shared__ int sm[256];
    int i = blockIdx.x * 256 + threadIdx.x;
    int s = 0, d = 0;
    if (i < n) {
#pragma unroll
        for (int g = 0; g < G_SL; g++) {
            s += Gsrc[(size_t)g * n + i];
            d += Gdst[(size_t)g * n + i];
        }
        norm_src[i] = s > 0 ? rsqrtf((float)s) : 0.f;
        norm_dst[i] = d > 0 ? rsqrtf((float)d) : 0.f;
    }
    sm[threadIdx.x] = (i < n) ? d : 0;
    __syncthreads();
    for (int off = 1; off < 256; off <<= 1) {
        int t = (threadIdx.x >= (unsigned)off) ? sm[threadIdx.x - off] : 0;
        __syncthreads();
        sm[threadIdx.x] += t;
        __syncthreads();
    }
    if (i < n) row_off[i + 1] = sm[threadIdx.x];   // raw: in-block inclusive
    if (threadIdx.x == 255) bsum[blockIdx.x] = sm[255];
}

// ---------------- pass 3: finalize row_off (global exclusive) + per-slice start offsets ----------------
__global__ __launch_bounds__(256)
void finalize_kernel(int* __restrict__ row_off, const int* __restrict__ bsum,
                     const ushort* __restrict__ Gdst, int* __restrict__ Goff, int n) {
    __shared__ int sm[256];
    const int b = blockIdx.x;
    const int t = threadIdx.x;
    sm[t] = (t < b) ? bsum[t] : 0;
    __syncthreads();
#pragma unroll
    for (int off = 128; off > 0; off >>= 1) {
        if (t < off) sm[t] += sm[t + off];
        __syncthreads();
    }
    const int excl = sm[0];
    const int v = b * 256 + t;
    if (v >= n) return;
    int raw = row_off[v];                       // each index touched only by its own thread
    int start = excl + ((t == 0) ? 0 : raw);
    if (v == n - 1) {
        int rawn = row_off[n];
        row_off[n] = excl + rawn;
    }
    row_off[v] = start;
    int run = start;
#pragma unroll
    for (int g = 0; g < G_SL; g++) {
        size_t idx = (size_t)g * n + v;
        Goff[idx] = run;
        run += Gdst[idx];
    }
}

// ---------------- edge placement (counting sort; int LDS cursors seeded with global offsets) ----------------
__global__ __launch_bounds__(1024)
void place_kernel(const int* __restrict__ src, const int* __restrict__ dst,
                  const int* __restrict__ Goff, int* __restrict__ edge_src, int n, int E) {
    __shared__ int cur[NRP];   // 51.2KB
    const int p = blockIdx.x / G_SL;
    const int g = blockIdx.x % G_SL;
    const int base = p * NRP;
    const int lim = min(NRP, n - base);
    for (int i = threadIdx.x; i < lim; i += 1024)
        cur[i] = Goff[(size_t)g * n + base + i];
    __syncthreads();
    const int Epg = (E + G_SL - 1) / G_SL;
    const int e0 = g * Epg;
    const int e1 = min(E, e0 + Epg);
    for (int i = e0 + (int)threadIdx.x; i < e1; i += 1024) {
        int d = dst[i];
        unsigned dd = (unsigned)(d - base);
        if (dd < (unsigned)lim) {
            int pos = atomicAdd(&cur[dd], 1);
            edge_src[pos] = src[i];
        }
    }
}

// ---------------- GEMM1 (MFMA, bf16): h1g(bf16) = (x @ W1) * norm_src ----------------
// BM=64, BK=32, 4 waves; wave w owns cols [w*32, w*32+32) x all 64 rows. A staged in LDS
// fragment-linear (conflict-free ds_write/ds_read_b128), 2-deep register FIFO on the x load,
// full k-loop unroll so all slot/buffer indices are static. B from L2 per-lane, 1 ahead.
#define BM 64
__global__ __launch_bounds__(256)
void gemm1_mfma(const float* __restrict__ x, const ushort* __restrict__ Wt,
                const float* __restrict__ norm_src, ushort* __restrict__ h1g, int n) {
    __shared__ __align__(16) ushort Al[2][4][64][8];   // [buf][mi][flane][8] = 8KB

    const int tid = threadIdx.x;
    const int lane = tid & 63;
    const int w = tid >> 6;
    const int l15 = lane & 15;
    const int lq = lane >> 4;
    const int bm = blockIdx.x * BM;

    // A staging: thread t stages fragment (mi=t>>6, flane=t&63)
    const int smi = tid >> 6;
    const int sflane = tid & 63;
    const int srow = smi * 16 + (tid & 15);
    const int skc = (tid >> 4) & 3;
    const int grow = bm + srow;
    const bool arok = grow < n;
    const float* xrow = x + (size_t)(arok ? grow : 0) * F0 + skc * 8;

    const size_t bg0 = (size_t)((w * 2 + 0) * 16 + l15) * F0 + lq * 8;
    const size_t bg1 = (size_t)((w * 2 + 1) * 16 + l15) * F0 + lq * 8;

    f32x4 acc[4][2] = {};
    float4 sa0, sa1;   // FIFO slot A
    float4 sb0, sb1;   // FIFO slot B
    bf16x8 bcur0, bcur1, bnxt0, bnxt1;

    auto loadA_A = [&](int k0) {
        if (arok) {
            sa0 = *reinterpret_cast<const float4*>(xrow + k0);
            sa1 = *reinterpret_cast<const float4*>(xrow + k0 + 4);
        } else { sa0 = make_float4(0.f, 0.f, 0.f, 0.f); sa1 = sa0; }
    };
    auto loadA_B = [&](int k0) {
        if (arok) {
            sb0 = *reinterpret_cast<const float4*>(xrow + k0);
            sb1 = *reinterpret_cast<const float4*>(xrow + k0 + 4);
        } else { sb0 = make_float4(0.f, 0.f, 0.f, 0.f); sb1 = sb0; }
    };
    auto stage = [&](int buf, const float4& c0, const float4& c1) {
        float cf[8] = {c0.x, c0.y, c0.z, c0.w, c1.x, c1.y, c1.z, c1.w};
        uint hu[4];
#pragma unroll
        for (int j = 0; j < 4; j++) {
            __hip_bfloat162 h2 = __float22bfloat162_rn(make_float2(cf[2 * j], cf[2 * j + 1]));
            __builtin_memcpy(&hu[j], &h2, 4);
        }
        *reinterpret_cast<uint4*>(&Al[buf][smi][sflane][0]) = make_uint4(hu[0], hu[1], hu[2], hu[3]);
    };
    auto loadB = [&](int k0, bf16x8& b0, bf16x8& b1) {
        b0 = *reinterpret_cast<const bf16x8*>(Wt + bg0 + k0);
        b1 = *reinterpret_cast<const bf16x8*>(Wt + bg1 + k0);
    };
    auto compute = [&](int buf, bf16x8 b0, bf16x8 b1) {
#pragma unroll
        for (int mi = 0; mi < 4; mi++) {
            bf16x8 a = *reinterpret_cast<const bf16x8*>(&Al[buf][mi][lane][0]);
            acc[mi][0] = __builtin_amdgcn_mfma_f32_16x16x32_bf16(a, b0, acc[mi][0], 0, 0, 0);
            acc[mi][1] = __builtin_amdgcn_mfma_f32_16x16x32_bf16(a, b1, acc[mi][1], 0, 0, 0);
        }
    };

    // prologue: A(0)->slotA->buf0; A(1)->slotB; B(0) in regs
    loadA_A(0);
    loadA_B(32);
    loadB(0, bcur0, bcur1);
    stage(0, sa0, sa1);
    __syncthreads();

    // invariant: A(m) lives in slot (m&1) for m>=1; stage of A(kt+1) happens at iter kt.
#pragma unroll
    for (int kt = 0; kt < 16; kt++) {
        const int cb = kt & 1;
        if (kt < 14) {                       // load A(kt+2) into slot (kt&1)
            if ((kt & 1) == 0) loadA_A((kt + 2) * 32);
            else               loadA_B((kt + 2) * 32);
        }
        if (kt < 15) loadB((kt + 1) * 32, bnxt0, bnxt1);
        compute(cb, bcur0, bcur1);
        if (kt < 15) {
            if (((kt + 1) & 1) == 0) stage(cb ^ 1, sa0, sa1);   // A(kt+1) from slotA
            else                     stage(cb ^ 1, sb0, sb1);   // A(kt+1) from slotB
            bcur0 = bnxt0; bcur1 = bnxt1;
            __syncthreads();
        }
    }

    // epilogue: C layout col=lane&15, row=4*(lane>>4)+reg; store bf16
#pragma unroll
    for (int mi = 0; mi < 4; mi++) {
        int rbase = bm + mi * 16 + lq * 4;
#pragma unroll
        for (int r = 0; r < 4; r++) {
            int row = rbase + r;
            if (row < n) {
                float ns = norm_src[row];
#pragma unroll
                for (int ni = 0; ni < 2; ni++) {
                    h1g[(size_t)row * F1 + w * 32 + ni * 16 + l15] = f2bf(acc[mi][ni][r] * ns);
                }
            }
        }
    }
}

// ---------------- Agg1: h1(bf16) = relu(segsum(h1g[src]) * norm_dst + b1), one wave per node ----------------
__global__ __launch_bounds__(256)
void agg1_kernel(const ushort* __restrict__ h1g, const int* __restrict__ row_off,
                 const int* __restrict__ edge_src, const float* __restrict__ norm_dst,
                 const float* __restrict__ b1, ushort* __restrict__ h1, int n) {
    int wid = (blockIdx.x * blockDim.x + threadIdx.x) >> 6;
    int lane = threadIdx.x & 63;
    if (wid >= n) return;
    int beg = row_off[wid], end = row_off[wid + 1];
    float a0 = 0.f, a1 = 0.f;
    int e = beg;
    for (; e + 7 < end; e += 8) {
        int s[8];
#pragma unroll
        for (int j = 0; j < 8; j++) s[j] = edge_src[e + j];
        uint v[8];
#pragma unroll
        for (int j = 0; j < 8; j++)
            v[j] = *reinterpret_cast<const uint*>(&h1g[(size_t)s[j] * F1 + lane * 2]);
#pragma unroll
        for (int j = 0; j < 8; j++) {
            a0 += __uint_as_float(v[j] << 16);
            a1 += __uint_as_float(v[j] & 0xffff0000u);
        }
    }
    for (; e < end; ++e) {
        int s = edge_src[e];
        uint v = *reinterpret_cast<const uint*>(&h1g[(size_t)s * F1 + lane * 2]);
        a0 += __uint_as_float(v << 16);
        a1 += __uint_as_float(v & 0xffff0000u);
    }
    float nd = norm_dst[wid];
    float o0 = fmaxf(a0 * nd + b1[lane * 2 + 0], 0.f);
    float o1 = fmaxf(a1 * nd + b1[lane * 2 + 1], 0.f);
    __hip_bfloat162 p2 = __float22bfloat162_rn(make_float2(o0, o1));
    uint pu; __builtin_memcpy(&pu, &p2, 4);
    *reinterpret_cast<uint*>(&h1[(size_t)wid * F1 + lane * 2]) = pu;
}

// ---------------- GEMM2: h2g(bf16) = (h1 @ W2) * norm_src  [n x 128] @ [128 x 40] ----------------
__global__ __launch_bounds__(256)
void gemm2_kernel(const ushort* __restrict__ h1, const float* __restrict__ W2,
                  const float* __restrict__ norm_src, ushort* __restrict__ h2g, int n) {
    __shared__ __align__(16) float W2s[F1][F2];
    for (int i = threadIdx.x; i < F1 * F2; i += 256)
        W2s[i / F2][i % F2] = W2[i];
    __syncthreads();
    int node = blockIdx.x * 256 + threadIdx.x;
    if (node >= n) return;
    float nrm = norm_src[node];
    f32x4 acc4[10] = {};
    const ushort* row = &h1[(size_t)node * F1];
    for (int kc = 0; kc < 16; kc++) {
        uint4 u = *reinterpret_cast<const uint4*>(&row[kc * 8]);
        uint uu[4] = {u.x, u.y, u.z, u.w};
        float f[8];
#pragma unroll
        for (int i = 0; i < 4; i++) {
            f[2 * i + 0] = __uint_as_float(uu[i] << 16);
            f[2 * i + 1] = __uint_as_float(uu[i] & 0xffff0000u);
        }
#pragma unroll
        for (int j = 0; j < 8; j++) {
#pragma unroll
            for (int c4 = 0; c4 < 10; c4++) {
                f32x4 wv = *reinterpret_cast<const f32x4*>(&W2s[kc * 8 + j][c4 * 4]);
                acc4[c4] += f[j] * wv;
            }
        }
    }
    ushort* orow = &h2g[(size_t)node * F2];
#pragma unroll
    for (int c4 = 0; c4 < 10; c4++) {
        f32x4 o = acc4[c4] * nrm;
        __hip_bfloat162 pa = __float22bfloat162_rn(make_float2(o[0], o[1]));
        __hip_bfloat162 pb = __float22bfloat162_rn(make_float2(o[2], o[3]));
        uint2 pk;
        __builtin_memcpy(&pk.x, &pa, 4);
        __builtin_memcpy(&pk.y, &pb, 4);
        *reinterpret_cast<uint2*>(&orow[c4 * 4]) = pk;
    }
}

// ---------------- Agg2: out = segsum(h2g[src]) * norm_dst + b2, one wave per node ----------------
__global__ __launch_bounds__(256)
void agg2_kernel(const ushort* __restrict__ h2g, const int* __restrict__ row_off,
                 const int* __restrict__ edge_src, const float* __restrict__ norm_dst,
                 const float* __restrict__ b2, float* __restrict__ out, int n) {
    int wid = (blockIdx.x * blockDim.x + threadIdx.x) >> 6;
    int lane = threadIdx.x & 63;
    if (wid >= n) return;
    int beg = row_off[wid], end = row_off[wid + 1];
    float a0 = 0.f, a1 = 0.f;
    int e = beg;
    const bool act = lane < 20;
    for (; e + 7 < end; e += 8) {
        int s[8];
#pragma unroll
        for (int j = 0; j < 8; j++) s[j] = edge_src[e + j];
        if (act) {
            uint v[8];
#pragma unroll
            for (int j = 0; j < 8; j++)
                v[j] = *reinterpret_cast<const uint*>(&h2g[(size_t)s[j] * F2 + lane * 2]);
#pragma unroll
            for (int j = 0; j < 8; j++) {
                a0 += __uint_as_float(v[j] << 16);
                a1 += __uint_as_float(v[j] & 0xffff0000u);
            }
        }
    }
    for (; e < end; ++e) {
        int s = edge_src[e];
        if (act) {
            uint v = *reinterpret_cast<const uint*>(&h2g[(size_t)s * F2 + lane * 2]);
            a0 += __uint_as_float(v << 16);
            a1 += __uint_as_float(v & 0xffff0000u);
        }
    }
    if (act) {
        float nd = norm_dst[wid];
        float o0 = a0 * nd + b2[lane * 2 + 0];
        float o1 = a1 * nd + b2[lane * 2 + 1];
        *reinterpret_cast<float2*>(&out[(size_t)wid * F2 + lane * 2]) = make_float2(o0, o1);
    }
}

extern "C" void kernel_launch(void* const* d_in, const int* in_sizes, int n_in,
                              void* d_out, int out_size, void* d_ws, size_t ws_size,
                              hipStream_t stream) {
    const float* x  = (const float*)d_in[0];
    const float* W1 = (const float*)d_in[1];
    const float* b1 = (const float*)d_in[2];
    const float* W2 = (const float*)d_in[3];
    const float* b2 = (const float*)d_in[4];
    const int* src  = (const int*)d_in[5];
    const int* dst  = (const int*)d_in[6];
    float* out = (float*)d_out;

    const int n = in_sizes[0] / F0;
    const int E = in_sizes[5];
    const int nb = (n + 255) / 256;
    const int P = (n + NRP - 1) / NRP;

    char* ws = (char*)d_ws;
    auto alloc = [&](size_t bytes) -> char* {
        char* p = ws;
        ws += (bytes + 255) & ~(size_t)255;
        return p;
    };
    int* row_off   = (int*)alloc((size_t)(n + 1) * 4);
    int* bsum      = (int*)alloc(256 * 4);
    int* edge_srcs = (int*)alloc((size_t)E * 4);
    float* norm_src_d = (float*)alloc((size_t)n * 4);
    float* norm_dst_d = (float*)alloc((size_t)n * 4);
    ushort* W1t = (ushort*)alloc((size_t)F1 * F0 * 2);
    ushort* h1g = (ushort*)alloc((size_t)n * F1 * 2);   // bf16 (12.8MB)
    ushort* h1  = (ushort*)alloc((size_t)n * F1 * 2);   // bf16 (12.8MB)
    ushort* h2g = h1g;   // reuse after agg1: n*F2*2 <= n*F1*2

    // aliasing (dead before hosts go live):
    //   Gsrc/Gdst (ushort counts, 2 * G_SL*n*2 = 12.8MB) -> h1g region (live from gemm1)
    //   Goff      (int offsets,       G_SL*n*4 = 12.8MB) -> h1  region (live from agg1)
    ushort* Gsrc = (ushort*)h1g;
    ushort* Gdst = Gsrc + (size_t)G_SL * n;
    int* Goff = (int*)h1;

    hist_kernel<<<P * G_SL, 1024, 0, stream>>>(src, dst, Gsrc, Gdst, W1, W1t, n, E);
    scanA_kernel<<<nb, 256, 0, stream>>>(Gsrc, Gdst, norm_src_d, norm_dst_d, row_off, bsum, n);
    finalize_kernel<<<nb, 256, 0, stream>>>(row_off, bsum, Gdst, Goff, n);
    place_kernel<<<P * G_SL, 1024, 0, stream>>>(src, dst, Goff, edge_srcs, n, E);
    gemm1_mfma<<<(n + BM - 1) / BM, 256, 0, stream>>>(x, W1t, norm_src_d, h1g, n);
    agg1_kernel<<<(n + 3) / 4, 256, 0, stream>>>(h1g, row_off, edge_srcs, norm_dst_d, b1, h1, n);
    gemm2_kernel<<<(n + 255) / 256, 256, 0, stream>>>(h1, W2, norm_src_d, h2g, n);
    agg2_kernel<<<(n + 3) / 4, 256, 0, stream>>>(h2g, row_off, edge_srcs, norm_dst_d, b2, out, n);
}

// Round 9
// 191.817 us; speedup vs baseline: 2.6278x; 1.0033x over previous
//
#include <hip/hip_runtime.h>
#include <hip/hip_bf16.h>

#define F0 512
#define F1 128
#define F2 40

#define NRP 12800   // nodes per histogram partition
#define G_SL 64     // edge slices

typedef __attribute__((ext_vector_type(8))) short bf16x8;
typedef __attribute__((ext_vector_type(4))) float f32x4;

__device__ inline ushort f2bf(float f) {
    union { float f; uint u; } v; v.f = f;
    uint u = v.u;
    uint r = u + 0x7fffu + ((u >> 16) & 1u);   // RNE
    return (ushort)(r >> 16);
}

// ---------------- pass 1: per-slice histograms + fused W1 preconvert ----------------
// grid = P * G_SL = 256 blocks of 1024 threads.
__global__ __launch_bounds__(1024)
void hist_kernel(const int* __restrict__ src, const int* __restrict__ dst,
                 ushort* __restrict__ Gsrc, ushort* __restrict__ Gdst,
                 const float* __restrict__ W1, ushort* __restrict__ Wt, int n, int E) {
    // fused W1 -> bf16 transpose: first 64 blocks cover 64*1024 = 65536 = F0*F1 elems
    if (blockIdx.x < (F0 * F1) / 1024) {
        int idx = blockIdx.x * 1024 + threadIdx.x;
        int k = idx >> 7, nn = idx & 127;
        Wt[nn * F0 + k] = f2bf(W1[idx]);
    }
    __shared__ uint cs[NRP / 2];
    __shared__ uint cd[NRP / 2];
    const int p = blockIdx.x / G_SL;
    const int g = blockIdx.x % G_SL;
    const int base = p * NRP;
    for (int i = threadIdx.x; i < NRP / 2; i += 1024) { cs[i] = 0; cd[i] = 0; }
    __syncthreads();
    const int Epg = (E + G_SL - 1) / G_SL;
    const int e0 = g * Epg;
    const int e1 = min(E, e0 + Epg);
    for (int i = e0 + (int)threadIdx.x; i < e1; i += 1024) {
        int s = src[i], d = dst[i];
        unsigned so = (unsigned)(s - base);
        unsigned dd = (unsigned)(d - base);
        if (so < (unsigned)NRP) atomicAdd(&cs[so >> 1], 1u << ((so & 1) * 16));
        if (dd < (unsigned)NRP) atomicAdd(&cd[dd >> 1], 1u << ((dd & 1) * 16));
    }
    __syncthreads();
    const int lim = min(NRP, n - base);
    for (int i = threadIdx.x; i < lim; i += 1024) {
        uint pcs = cs[i >> 1], pcd = cd[i >> 1];
        int sh = (i & 1) * 16;
        Gsrc[(size_t)g * n + base + i] = (ushort)((pcs >> sh) & 0xffffu);
        Gdst[(size_t)g * n + base + i] = (ushort)((pcd >> sh) & 0xffffu);
    }
}

// ---------------- pass 2: degree sums + norms + per-256-block inclusive scan ----------------
__global__ __launch_bounds__(256)
void scanA_kernel(const ushort* __restrict__ Gsrc, const ushort* __restrict__ Gdst,
                  float* __restrict__ norm_src, float* __restrict__ norm_dst,
                  int* __restrict__ row_off, int* __restrict__ bsum, int n) {
    __shared__ int sm[256];
    int i = blockIdx.x * 256 + threadIdx.x;
    int s = 0, d = 0;
    if (i < n) {
#pragma unroll
        for (int g = 0; g < G_SL; g++) {
            s += Gsrc[(size_t)g * n + i];
            d += Gdst[(size_t)g * n + i];
        }
        norm_src[i] = s > 0 ? rsqrtf((float)s) : 0.f;
        norm_dst[i] = d > 0 ? rsqrtf((float)d) : 0.f;
    }
    sm[threadIdx.x] = (i < n) ? d : 0;
    __syncthreads();
    for (int off = 1; off < 256; off <<= 1) {
        int t = (threadIdx.x >= (unsigned)off) ? sm[threadIdx.x - off] : 0;
        __syncthreads();
        sm[threadIdx.x] += t;
        __syncthreads();
    }
    if (i < n) row_off[i + 1] = sm[threadIdx.x];   // raw: in-block inclusive
    if (threadIdx.x == 255) bsum[blockIdx.x] = sm[255];
}

// ---------------- pass 3: finalize row_off (global exclusive) + per-slice start offsets ----------------
__global__ __launch_bounds__(256)
void finalize_kernel(int* __restrict__ row_off, const int* __restrict__ bsum,
                     const ushort* __restrict__ Gdst, int* __restrict__ Goff, int n) {
    __shared__ int sm[256];
    const int b = blockIdx.x;
    const int t = threadIdx.x;
    sm[t] = (t < b) ? bsum[t] : 0;
    __syncthreads();
#pragma unroll
    for (int off = 128; off > 0; off >>= 1) {
        if (t < off) sm[t] += sm[t + off];
        __syncthreads();
    }
    const int excl = sm[0];
    const int v = b * 256 + t;
    if (v >= n) return;
    int raw = row_off[v];                       // each index touched only by its own thread
    int start = excl + ((t == 0) ? 0 : raw);
    if (v == n - 1) {
        int rawn = row_off[n];
        row_off[n] = excl + rawn;
    }
    row_off[v] = start;
    int run = start;
#pragma unroll
    for (int g = 0; g < G_SL; g++) {
        size_t idx = (size_t)g * n + v;
        Goff[idx] = run;
        run += Gdst[idx];
    }
}

// ---------------- edge placement (counting sort; int LDS cursors seeded with global offsets) ----------------
__global__ __launch_bounds__(1024)
void place_kernel(const int* __restrict__ src, const int* __restrict__ dst,
                  const int* __restrict__ Goff, int* __restrict__ edge_src, int n, int E) {
    __shared__ int cur[NRP];   // 51.2KB
    const int p = blockIdx.x / G_SL;
    const int g = blockIdx.x % G_SL;
    const int base = p * NRP;
    const int lim = min(NRP, n - base);
    for (int i = threadIdx.x; i < lim; i += 1024)
        cur[i] = Goff[(size_t)g * n + base + i];
    __syncthreads();
    const int Epg = (E + G_SL - 1) / G_SL;
    const int e0 = g * Epg;
    const int e1 = min(E, e0 + Epg);
    for (int i = e0 + (int)threadIdx.x; i < e1; i += 1024) {
        int d = dst[i];
        unsigned dd = (unsigned)(d - base);
        if (dd < (unsigned)lim) {
            int pos = atomicAdd(&cur[dd], 1);
            edge_src[pos] = src[i];
        }
    }
}

// ---------------- GEMM1 (MFMA, bf16): h1g(bf16) = (x @ W1) * norm_src ----------------
// BM=64, BK=32, 4 waves; wave w owns cols [w*32, w*32+32) x all 64 rows. A staged in LDS
// fragment-linear (conflict-free). x prefetch via 4-deep register FIFO with ALL indices
// written as literals (macros + explicit 4-step loop body) -- no lambdas, no mega-unroll,
// avoids the clang ICE hit in R8. Schedule: at iter kt load A(kt+4), stage A(kt+1).
#define BM 64

#define CVT2(dst, a, b) { __hip_bfloat162 _t2 = __float22bfloat162_rn(make_float2(a, b)); __builtin_memcpy(&dst, &_t2, 4); }

#define LOADA(s0, s1, k0)                                                 \
    if (arok) {                                                           \
        s0 = *reinterpret_cast<const float4*>(xrow + (k0));               \
        s1 = *reinterpret_cast<const float4*>(xrow + (k0) + 4);           \
    } else { s0 = make_float4(0.f, 0.f, 0.f, 0.f); s1 = s0; }

#define STAGE(buf, s0, s1) {                                              \
    uint _h0, _h1, _h2, _h3;                                              \
    CVT2(_h0, s0.x, s0.y); CVT2(_h1, s0.z, s0.w);                         \
    CVT2(_h2, s1.x, s1.y); CVT2(_h3, s1.z, s1.w);                         \
    *reinterpret_cast<uint4*>(&Al[buf][smi][sflane][0]) = make_uint4(_h0, _h1, _h2, _h3); }

#define LOADB(k0, b0, b1) {                                               \
    b0 = *reinterpret_cast<const bf16x8*>(bp0 + (k0));                    \
    b1 = *reinterpret_cast<const bf16x8*>(bp1 + (k0)); }

#define COMPUTE(buf, b0, b1) {                                                         \
    bf16x8 _a0 = *reinterpret_cast<const bf16x8*>(&Al[buf][0][lane][0]);               \
    bf16x8 _a1 = *reinterpret_cast<const bf16x8*>(&Al[buf][1][lane][0]);               \
    bf16x8 _a2 = *reinterpret_cast<const bf16x8*>(&Al[buf][2][lane][0]);               \
    bf16x8 _a3 = *reinterpret_cast<const bf16x8*>(&Al[buf][3][lane][0]);               \
    acc[0][0] = __builtin_amdgcn_mfma_f32_16x16x32_bf16(_a0, b0, acc[0][0], 0, 0, 0);  \
    acc[0][1] = __builtin_amdgcn_mfma_f32_16x16x32_bf16(_a0, b1, acc[0][1], 0, 0, 0);  \
    acc[1][0] = __builtin_amdgcn_mfma_f32_16x16x32_bf16(_a1, b0, acc[1][0], 0, 0, 0);  \
    acc[1][1] = __builtin_amdgcn_mfma_f32_16x16x32_bf16(_a1, b1, acc[1][1], 0, 0, 0);  \
    acc[2][0] = __builtin_amdgcn_mfma_f32_16x16x32_bf16(_a2, b0, acc[2][0], 0, 0, 0);  \
    acc[2][1] = __builtin_amdgcn_mfma_f32_16x16x32_bf16(_a2, b1, acc[2][1], 0, 0, 0);  \
    acc[3][0] = __builtin_amdgcn_mfma_f32_16x16x32_bf16(_a3, b0, acc[3][0], 0, 0, 0);  \
    acc[3][1] = __builtin_amdgcn_mfma_f32_16x16x32_bf16(_a3, b1, acc[3][1], 0, 0, 0); }

__global__ __launch_bounds__(256)
void gemm1_mfma(const float* __restrict__ x, const ushort* __restrict__ Wt,
                const float* __restrict__ norm_src, ushort* __restrict__ h1g, int n) {
    __shared__ __align__(16) ushort Al[2][4][64][8];   // [buf][mi][flane][8] = 8KB

    const int tid = threadIdx.x;
    const int lane = tid & 63;
    const int w = tid >> 6;
    const int l15 = lane & 15;
    const int lq = lane >> 4;
    const int bm = blockIdx.x * BM;

    // A staging: thread t stages fragment (mi=t>>6, flane=t&63)
    const int smi = tid >> 6;
    const int sflane = tid & 63;
    const int srow = smi * 16 + (tid & 15);
    const int skc = (tid >> 4) & 3;
    const int grow = bm + srow;
    const bool arok = grow < n;
    const float* xrow = x + (size_t)(arok ? grow : 0) * F0 + skc * 8;

    const ushort* bp0 = Wt + (size_t)((w * 2 + 0) * 16 + l15) * F0 + lq * 8;
    const ushort* bp1 = Wt + (size_t)((w * 2 + 1) * 16 + l15) * F0 + lq * 8;

    f32x4 acc[4][2] = {};
    float4 f00, f01, f10, f11, f20, f21, f30, f31;   // FIFO slots 0..3 (A(k) in slot k&3)
    bf16x8 bcur0, bcur1, bnxt0, bnxt1;

    // prologue: fill 4-deep FIFO with A(0..3); B(0); stage A(0) -> buf0
    LOADA(f00, f01, 0);
    LOADA(f10, f11, 32);
    LOADA(f20, f21, 64);
    LOADA(f30, f31, 96);
    LOADB(0, bcur0, bcur1);
    STAGE(0, f00, f01);
    __syncthreads();

    // steady state: kt2 = 0..2, kt = kb..kb+3 (kb = 4*kt2). All loadA targets kt+4 <= 15.
    for (int kt2 = 0; kt2 < 3; kt2++) {
        const int kb = kt2 * 4;
        // kt = kb+0 (buf 0): load A(kb+4)->slot0, B(kb+1); stage A(kb+1) from slot1
        LOADA(f00, f01, (kb + 4) * 32);
        LOADB((kb + 1) * 32, bnxt0, bnxt1);
        COMPUTE(0, bcur0, bcur1);
        STAGE(1, f10, f11);
        bcur0 = bnxt0; bcur1 = bnxt1;
        __syncthreads();
        // kt = kb+1 (buf 1): load A(kb+5)->slot1, B(kb+2); stage A(kb+2) from slot2
        LOADA(f10, f11, (kb + 5) * 32);
        LOADB((kb + 2) * 32, bnxt0, bnxt1);
        COMPUTE(1, bcur0, bcur1);
        STAGE(0, f20, f21);
        bcur0 = bnxt0; bcur1 = bnxt1;
        __syncthreads();
        // kt = kb+2 (buf 0): load A(kb+6)->slot2, B(kb+3); stage A(kb+3) from slot3
        LOADA(f20, f21, (kb + 6) * 32);
        LOADB((kb + 3) * 32, bnxt0, bnxt1);
        COMPUTE(0, bcur0, bcur1);
        STAGE(1, f30, f31);
        bcur0 = bnxt0; bcur1 = bnxt1;
        __syncthreads();
        // kt = kb+3 (buf 1): load A(kb+7)->slot3, B(kb+4); stage A(kb+4) from slot0
        LOADA(f30, f31, (kb + 7) * 32);
        LOADB((kb + 4) * 32, bnxt0, bnxt1);
        COMPUTE(1, bcur0, bcur1);
        STAGE(0, f00, f01);
        bcur0 = bnxt0; bcur1 = bnxt1;
        __syncthreads();
    }

    // tail: kt = 12..15 (no more A loads; slots 1..3 hold A(13..15))
    LOADB(13 * 32, bnxt0, bnxt1);
    COMPUTE(0, bcur0, bcur1);
    STAGE(1, f10, f11);                 // A(13)
    bcur0 = bnxt0; bcur1 = bnxt1;
    __syncthreads();

    LOADB(14 * 32, bnxt0, bnxt1);
    COMPUTE(1, bcur0, bcur1);
    STAGE(0, f20, f21);                 // A(14)
    bcur0 = bnxt0; bcur1 = bnxt1;
    __syncthreads();

    LOADB(15 * 32, bnxt0, bnxt1);
    COMPUTE(0, bcur0, bcur1);
    STAGE(1, f30, f31);                 // A(15)
    bcur0 = bnxt0; bcur1 = bnxt1;
    __syncthreads();

    COMPUTE(1, bcur0, bcur1);

    // epilogue: C layout col=lane&15, row=4*(lane>>4)+reg; store bf16
#pragma unroll
    for (int mi = 0; mi < 4; mi++) {
        int rbase = bm + mi * 16 + lq * 4;
#pragma unroll
        for (int r = 0; r < 4; r++) {
            int row = rbase + r;
            if (row < n) {
                float ns = norm_src[row];
#pragma unroll
                for (int ni = 0; ni < 2; ni++) {
                    h1g[(size_t)row * F1 + w * 32 + ni * 16 + l15] = f2bf(acc[mi][ni][r] * ns);
                }
            }
        }
    }
}

// ---------------- Agg1: h1(bf16) = relu(segsum(h1g[src]) * norm_dst + b1), one wave per node ----------------
__global__ __launch_bounds__(256)
void agg1_kernel(const ushort* __restrict__ h1g, const int* __restrict__ row_off,
                 const int* __restrict__ edge_src, const float* __restrict__ norm_dst,
                 const float* __restrict__ b1, ushort* __restrict__ h1, int n) {
    int wid = (blockIdx.x * blockDim.x + threadIdx.x) >> 6;
    int lane = threadIdx.x & 63;
    if (wid >= n) return;
    int beg = row_off[wid], end = row_off[wid + 1];
    float a0 = 0.f, a1 = 0.f;
    int e = beg;
    for (; e + 7 < end; e += 8) {
        int s[8];
#pragma unroll
        for (int j = 0; j < 8; j++) s[j] = edge_src[e + j];
        uint v[8];
#pragma unroll
        for (int j = 0; j < 8; j++)
            v[j] = *reinterpret_cast<const uint*>(&h1g[(size_t)s[j] * F1 + lane * 2]);
#pragma unroll
        for (int j = 0; j < 8; j++) {
            a0 += __uint_as_float(v[j] << 16);
            a1 += __uint_as_float(v[j] & 0xffff0000u);
        }
    }
    for (; e < end; ++e) {
        int s = edge_src[e];
        uint v = *reinterpret_cast<const uint*>(&h1g[(size_t)s * F1 + lane * 2]);
        a0 += __uint_as_float(v << 16);
        a1 += __uint_as_float(v & 0xffff0000u);
    }
    float nd = norm_dst[wid];
    float o0 = fmaxf(a0 * nd + b1[lane * 2 + 0], 0.f);
    float o1 = fmaxf(a1 * nd + b1[lane * 2 + 1], 0.f);
    __hip_bfloat162 p2 = __float22bfloat162_rn(make_float2(o0, o1));
    uint pu; __builtin_memcpy(&pu, &p2, 4);
    *reinterpret_cast<uint*>(&h1[(size_t)wid * F1 + lane * 2]) = pu;
}

// ---------------- GEMM2: h2g(bf16) = (h1 @ W2) * norm_src  [n x 128] @ [128 x 40] ----------------
__global__ __launch_bounds__(256)
void gemm2_kernel(const ushort* __restrict__ h1, const float* __restrict__ W2,
                  const float* __restrict__ norm_src, ushort* __restrict__ h2g, int n) {
    __shared__ __align__(16) float W2s[F1][F2];
    for (int i = threadIdx.x; i < F1 * F2; i += 256)
        W2s[i / F2][i % F2] = W2[i];
    __syncthreads();
    int node = blockIdx.x * 256 + threadIdx.x;
    if (node >= n) return;
    float nrm = norm_src[node];
    f32x4 acc4[10] = {};
    const ushort* row = &h1[(size_t)node * F1];
    for (int kc = 0; kc < 16; kc++) {
        uint4 u = *reinterpret_cast<const uint4*>(&row[kc * 8]);
        uint uu[4] = {u.x, u.y, u.z, u.w};
        float f[8];
#pragma unroll
        for (int i = 0; i < 4; i++) {
            f[2 * i + 0] = __uint_as_float(uu[i] << 16);
            f[2 * i + 1] = __uint_as_float(uu[i] & 0xffff0000u);
        }
#pragma unroll
        for (int j = 0; j < 8; j++) {
#pragma unroll
            for (int c4 = 0; c4 < 10; c4++) {
                f32x4 wv = *reinterpret_cast<const f32x4*>(&W2s[kc * 8 + j][c4 * 4]);
                acc4[c4] += f[j] * wv;
            }
        }
    }
    ushort* orow = &h2g[(size_t)node * F2];
#pragma unroll
    for (int c4 = 0; c4 < 10; c4++) {
        f32x4 o = acc4[c4] * nrm;
        __hip_bfloat162 pa = __float22bfloat162_rn(make_float2(o[0], o[1]));
        __hip_bfloat162 pb = __float22bfloat162_rn(make_float2(o[2], o[3]));
        uint2 pk;
        __builtin_memcpy(&pk.x, &pa, 4);
        __builtin_memcpy(&pk.y, &pb, 4);
        *reinterpret_cast<uint2*>(&orow[c4 * 4]) = pk;
    }
}

// ---------------- Agg2: out = segsum(h2g[src]) * norm_dst + b2, one wave per node ----------------
__global__ __launch_bounds__(256)
void agg2_kernel(const ushort* __restrict__ h2g, const int* __restrict__ row_off,
                 const int* __restrict__ edge_src, const float* __restrict__ norm_dst,
                 const float* __restrict__ b2, float* __restrict__ out, int n) {
    int wid = (blockIdx.x * blockDim.x + threadIdx.x) >> 6;
    int lane = threadIdx.x & 63;
    if (wid >= n) return;
    int beg = row_off[wid], end = row_off[wid + 1];
    float a0 = 0.f, a1 = 0.f;
    int e = beg;
    const bool act = lane < 20;
    for (; e + 7 < end; e += 8) {
        int s[8];
#pragma unroll
        for (int j = 0; j < 8; j++) s[j] = edge_src[e + j];
        if (act) {
            uint v[8];
#pragma unroll
            for (int j = 0; j < 8; j++)
                v[j] = *reinterpret_cast<const uint*>(&h2g[(size_t)s[j] * F2 + lane * 2]);
#pragma unroll
            for (int j = 0; j < 8; j++) {
                a0 += __uint_as_float(v[j] << 16);
                a1 += __uint_as_float(v[j] & 0xffff0000u);
            }
        }
    }
    for (; e < end; ++e) {
        int s = edge_src[e];
        if (act) {
            uint v = *reinterpret_cast<const uint*>(&h2g[(size_t)s * F2 + lane * 2]);
            a0 += __uint_as_float(v << 16);
            a1 += __uint_as_float(v & 0xffff0000u);
        }
    }
    if (act) {
        float nd = norm_dst[wid];
        float o0 = a0 * nd + b2[lane * 2 + 0];
        float o1 = a1 * nd + b2[lane * 2 + 1];
        *reinterpret_cast<float2*>(&out[(size_t)wid * F2 + lane * 2]) = make_float2(o0, o1);
    }
}

extern "C" void kernel_launch(void* const* d_in, const int* in_sizes, int n_in,
                              void* d_out, int out_size, void* d_ws, size_t ws_size,
                              hipStream_t stream) {
    const float* x  = (const float*)d_in[0];
    const float* W1 = (const float*)d_in[1];
    const float* b1 = (const float*)d_in[2];
    const float* W2 = (const float*)d_in[3];
    const float* b2 = (const float*)d_in[4];
    const int* src  = (const int*)d_in[5];
    const int* dst  = (const int*)d_in[6];
    float* out = (float*)d_out;

    const int n = in_sizes[0] / F0;
    const int E = in_sizes[5];
    const int nb = (n + 255) / 256;
    const int P = (n + NRP - 1) / NRP;

    char* ws = (char*)d_ws;
    auto alloc = [&](size_t bytes) -> char* {
        char* p = ws;
        ws += (bytes + 255) & ~(size_t)255;
        return p;
    };
    int* row_off   = (int*)alloc((size_t)(n + 1) * 4);
    int* bsum      = (int*)alloc(256 * 4);
    int* edge_srcs = (int*)alloc((size_t)E * 4);
    float* norm_src_d = (float*)alloc((size_t)n * 4);
    float* norm_dst_d = (float*)alloc((size_t)n * 4);
    ushort* W1t = (ushort*)alloc((size_t)F1 * F0 * 2);
    ushort* h1g = (ushort*)alloc((size_t)n * F1 * 2);   // bf16 (12.8MB)
    ushort* h1  = (ushort*)alloc((size_t)n * F1 * 2);   // bf16 (12.8MB)
    ushort* h2g = h1g;   // reuse after agg1: n*F2*2 <= n*F1*2

    // aliasing (dead before hosts go live):
    //   Gsrc/Gdst (ushort counts, 2 * G_SL*n*2 = 12.8MB) -> h1g region (live from gemm1)
    //   Goff      (int offsets,       G_SL*n*4 = 12.8MB) -> h1  region (live from agg1)
    ushort* Gsrc = (ushort*)h1g;
    ushort* Gdst = Gsrc + (size_t)G_SL * n;
    int* Goff = (int*)h1;

    hist_kernel<<<P * G_SL, 1024, 0, stream>>>(src, dst, Gsrc, Gdst, W1, W1t, n, E);
    scanA_kernel<<<nb, 256, 0, stream>>>(Gsrc, Gdst, norm_src_d, norm_dst_d, row_off, bsum, n);
    finalize_kernel<<<nb, 256, 0, stream>>>(row_off, bsum, Gdst, Goff, n);
    place_kernel<<<P * G_SL, 1024, 0, stream>>>(src, dst, Goff, edge_srcs, n, E);
    gemm1_mfma<<<(n + BM - 1) / BM, 256, 0, stream>>>(x, W1t, norm_src_d, h1g, n);
    agg1_kernel<<<(n + 3) / 4, 256, 0, stream>>>(h1g, row_off, edge_srcs, norm_dst_d, b1, h1, n);
    gemm2_kernel<<<(n + 255) / 256, 256, 0, stream>>>(h1, W2, norm_src_d, h2g, n);
    agg2_kernel<<<(n + 3) / 4, 256, 0, stream>>>(h2g, row_off, edge_srcs, norm_dst_d, b2, out, n);
}